// Round 1
// baseline (469.302 us; speedup 1.0000x reference)
//
#include <hip/hip_runtime.h>
#include <math.h>

namespace {

constexpr int T_   = 512;
constexpr int D_   = 512;
constexpr int H_   = 8;
constexpr int DH   = 64;
constexpr int BH   = 32;     // B*H
constexpr int NLAG = 64;
constexpr int KTOP = 18;
constexpr int M_   = 2048;   // B*T

__device__ __forceinline__ int lag_of(int li) { return (li < 63) ? (1 + 7 * li) : 511; }

// ---------------- generic 64x64-tiled transpose: out[C][R] = in[R][C] ---------
__global__ __launch_bounds__(256) void k_transpose(const float* __restrict__ in,
                                                   float* __restrict__ out,
                                                   int R, int C) {
  __shared__ float tile[64][65];
  const size_t zoff = (size_t)blockIdx.z * (size_t)R * (size_t)C;
  const float* inb = in + zoff;
  float* outb = out + zoff;
  const int r0 = blockIdx.y * 64, c0 = blockIdx.x * 64;
#pragma unroll
  for (int j = 0; j < 16; ++j) {
    int fid = threadIdx.x + 256 * j;
    int r = fid >> 6, c = fid & 63;
    tile[r][c] = inb[(size_t)(r0 + r) * C + (c0 + c)];
  }
  __syncthreads();
#pragma unroll
  for (int j = 0; j < 16; ++j) {
    int fid = threadIdx.x + 256 * j;
    int c = fid >> 6, r = fid & 63;
    outb[(size_t)(c0 + c) * R + (r0 + r)] = tile[r][c];
  }
}

// ---------------- 64x64 output tile GEMM core: C += A^T(KxM) * B(KxN) ---------
__device__ __forceinline__ void gemm_tile(const float* __restrict__ AT,
                                          const float* __restrict__ BW,
                                          int Mdim, int Ndim, int Kdim,
                                          int m0, int n0, float acc[4][4]) {
  __shared__ float As[32 * 64];
  __shared__ float Bs[32 * 64];
  const int tid = threadIdx.x;
  const int tx = tid & 15, ty = tid >> 4;
  for (int k0 = 0; k0 < Kdim; k0 += 32) {
#pragma unroll
    for (int j = 0; j < 2; ++j) {
      int fid = tid + 256 * j;
      int r = fid >> 4, c4 = (fid & 15) * 4;
      *(float4*)(As + r * 64 + c4) = *(const float4*)(AT + (size_t)(k0 + r) * Mdim + m0 + c4);
      *(float4*)(Bs + r * 64 + c4) = *(const float4*)(BW + (size_t)(k0 + r) * Ndim + n0 + c4);
    }
    __syncthreads();
#pragma unroll
    for (int kk = 0; kk < 32; ++kk) {
      float4 a4 = *(const float4*)(As + kk * 64 + 4 * ty);
      float4 b4 = *(const float4*)(Bs + kk * 64 + 4 * tx);
      float av[4] = {a4.x, a4.y, a4.z, a4.w};
      float bw[4] = {b4.x, b4.y, b4.z, b4.w};
#pragma unroll
      for (int i = 0; i < 4; ++i)
#pragma unroll
        for (int j = 0; j < 4; ++j)
          acc[i][j] = fmaf(av[i], bw[j], acc[i][j]);
    }
    __syncthreads();
  }
}

// ---------------- QKV projection: out in (B,H,T,Dh) layout ---------------------
__global__ __launch_bounds__(256) void k_qkv_gemm(
    const float* __restrict__ xT,
    const float* __restrict__ Wq, const float* __restrict__ Wk, const float* __restrict__ Wv,
    const float* __restrict__ bq, const float* __restrict__ bk, const float* __restrict__ bv,
    float* __restrict__ Qo, float* __restrict__ Ko, float* __restrict__ Vo) {
  const int z = blockIdx.z;
  const float* W  = (z == 0) ? Wq : (z == 1) ? Wk : Wv;
  const float* bb = (z == 0) ? bq : (z == 1) ? bk : bv;
  float* out      = (z == 0) ? Qo : (z == 1) ? Ko : Vo;
  const int n0 = blockIdx.x * 64, m0 = blockIdx.y * 64;
  const int tx = threadIdx.x & 15, ty = threadIdx.x >> 4;
  float acc[4][4];
#pragma unroll
  for (int i = 0; i < 4; ++i)
#pragma unroll
    for (int j = 0; j < 4; ++j) acc[i][j] = bb[n0 + 4 * tx + j];
  gemm_tile(xT, W, M_, D_, D_, m0, n0, acc);
  const int b = m0 >> 9;           // 512 rows (t) per batch
  const int trow = m0 & 511;
  const int h = n0 >> 6;           // 64 cols per head
  float* outb = out + ((size_t)(b * H_ + h) * T_ + trow) * DH;
#pragma unroll
  for (int i = 0; i < 4; ++i) {
    float4 st = make_float4(acc[i][0], acc[i][1], acc[i][2], acc[i][3]);
    *(float4*)(outb + (size_t)(4 * ty + i) * DH + 4 * tx) = st;
  }
}

// ---------------- L2 normalize over time, in place, Q then K ------------------
__global__ __launch_bounds__(256) void k_l2norm(float* __restrict__ QK) {
  float* Xb = QK + (size_t)blockIdx.y * ((size_t)BH * T_ * DH)
                 + (size_t)blockIdx.x * T_ * DH;
  const int tid = threadIdx.x;
  __shared__ float red[256];
  __shared__ float sinv[64];
  float ss = 0.f;
  for (int i = 0; i < 128; ++i) {
    float v = Xb[tid + 256 * i];     // = Xb[t*64 + d], d = tid&63
    ss += v * v;
  }
  red[tid] = ss;
  __syncthreads();
  if (tid < 64) {
    float s = red[tid] + red[tid + 64] + red[tid + 128] + red[tid + 192];
    sinv[tid] = 1.0f / sqrtf(fmaxf(s, 1e-8f));
  }
  __syncthreads();
  const float inv = sinv[tid & 63];
  for (int i = 0; i < 128; ++i) Xb[tid + 256 * i] *= inv;
}

// ---------------- cov[l,d,c] = sum_t K[(t-lag)%T,d] * Q[t,c]; + scores --------
__global__ __launch_bounds__(256) void k_cov(const float* __restrict__ Qh,
                                             const float* __restrict__ Kh,
                                             float* __restrict__ cov,
                                             float* __restrict__ score,
                                             const float* __restrict__ p_lambda) {
  const int bh = blockIdx.x;
  const int l  = blockIdx.y;                       // 0 => lag 0 (cov0), 1..64 => candidates
  const int lag = (l == 0) ? 0 : lag_of(l - 1);
  const float* Qb = Qh + (size_t)bh * T_ * DH;
  const float* Kb = Kh + (size_t)bh * T_ * DH;
  __shared__ float Ks[32 * 64];
  __shared__ float Qs[32 * 64];
  __shared__ float red[256];
  const int tid = threadIdx.x;
  const int tx = tid & 15, ty = tid >> 4;
  float acc[4][4] = {};
  for (int t0 = 0; t0 < T_; t0 += 32) {
#pragma unroll
    for (int j = 0; j < 2; ++j) {
      int fid = tid + 256 * j;
      int r = fid >> 4, c4 = (fid & 15) * 4;
      int tq = t0 + r;
      int tk = (tq - lag) & 511;
      *(float4*)(Ks + r * 64 + c4) = *(const float4*)(Kb + (size_t)tk * DH + c4);
      *(float4*)(Qs + r * 64 + c4) = *(const float4*)(Qb + (size_t)tq * DH + c4);
    }
    __syncthreads();
#pragma unroll
    for (int kk = 0; kk < 32; ++kk) {
      float4 a4 = *(const float4*)(Ks + kk * 64 + 4 * ty);
      float4 b4 = *(const float4*)(Qs + kk * 64 + 4 * tx);
      float av[4] = {a4.x, a4.y, a4.z, a4.w};
      float bw[4] = {b4.x, b4.y, b4.z, b4.w};
#pragma unroll
      for (int i = 0; i < 4; ++i)
#pragma unroll
        for (int j = 0; j < 4; ++j)
          acc[i][j] = fmaf(av[i], bw[j], acc[i][j]);
    }
    __syncthreads();
  }
  float* cb = cov + ((size_t)l * BH + bh) * 4096;
#pragma unroll
  for (int i = 0; i < 4; ++i) {
    float4 st = make_float4(acc[i][0], acc[i][1], acc[i][2], acc[i][3]);
    *(float4*)(cb + (size_t)(4 * ty + i) * 64 + 4 * tx) = st;
  }
  // score = lam*diag_abs + (1-lam)*(total_abs - diag_abs), only for l>=1
  float labs = 0.f, ldiag = 0.f;
#pragma unroll
  for (int i = 0; i < 4; ++i)
#pragma unroll
    for (int j = 0; j < 4; ++j) labs += fabsf(acc[i][j]);
  if (tx == ty) {
#pragma unroll
    for (int i = 0; i < 4; ++i) ldiag += fabsf(acc[i][i]);
  }
  red[tid] = labs;
  __syncthreads();
  for (int s = 128; s > 0; s >>= 1) {
    if (tid < s) red[tid] += red[tid + s];
    __syncthreads();
  }
  float total = red[0];
  __syncthreads();
  red[tid] = ldiag;
  __syncthreads();
  for (int s = 128; s > 0; s >>= 1) {
    if (tid < s) red[tid] += red[tid + s];
    __syncthreads();
  }
  if (tid == 0 && l > 0) {
    float lam = fminf(fmaxf(p_lambda[0], 0.f), 1.f);
    float diag = red[0];
    score[(size_t)bh * NLAG + (l - 1)] = lam * diag + (1.f - lam) * (total - diag);
  }
}

// ---------------- top-18 selection + lag-mix weights --------------------------
__global__ void k_topk(const float* __restrict__ score, int* __restrict__ sel,
                       float* __restrict__ wgt, const float* __restrict__ p_log_tau_lag) {
  const int bh = threadIdx.x;
  if (bh >= BH) return;
  const float* s = score + (size_t)bh * NLAG;
  float ts[KTOP];
  int ti[KTOP];
  unsigned long long used = 0ull;
  for (int k = 0; k < KTOP; ++k) {
    float best = -1e30f;
    int bi = 0;
    for (int i = 0; i < NLAG; ++i) {
      if (((used >> i) & 1ull) == 0ull && s[i] > best) { best = s[i]; bi = i; }
    }
    used |= (1ull << bi);
    ts[k] = best;
    ti[k] = bi;
  }
  const float tau_lag = fmaxf(expf(p_log_tau_lag[0]), 1e-4f);
  const float mx = ts[0];
  float e[KTOP];
  float sum = 0.f;
  for (int k = 0; k < KTOP; ++k) { e[k] = expf((ts[k] - mx) / tau_lag); sum += e[k]; }
  const float rs = 1.0f / sum;
  for (int k = 0; k < KTOP; ++k) {
    sel[bh * KTOP + k] = ti[k];
    wgt[bh * KTOP + k] = e[k] * rs;
  }
}

// ---------------- row softmax of the 19 selected cov matrices -----------------
__global__ __launch_bounds__(256) void k_attsm(const float* __restrict__ cov,
                                               const int* __restrict__ sel,
                                               float* __restrict__ att,
                                               const float* __restrict__ p_log_tau) {
  const int bh = blockIdx.x;
  const int m  = blockIdx.y;                 // 0 => inst (lag 0); 1..18 => top lags
  const int slot = (m == 0) ? 0 : (1 + sel[bh * KTOP + (m - 1)]);
  const float* cb = cov + ((size_t)slot * BH + bh) * 4096;
  float* ab = att + ((size_t)m * BH + bh) * 4096;
  const float itau = 1.0f / fmaxf(expf(p_log_tau[0]), 1e-4f);
  const int lane = threadIdx.x & 63;
  const int wv = threadIdx.x >> 6;
  for (int d = wv; d < 64; d += 4) {
    float v = cb[d * 64 + lane] * itau;
    float mx = v;
#pragma unroll
    for (int off = 32; off > 0; off >>= 1) mx = fmaxf(mx, __shfl_xor(mx, off));
    float e = expf(v - mx);
    float sm = e;
#pragma unroll
    for (int off = 32; off > 0; off >>= 1) sm += __shfl_xor(sm, off);
    ab[d * 64 + lane] = e / sm;
  }
}

// ---------------- out_h[t,c] = sum_m s_m * sum_d V[(t-lag_m)%T,d]*att_m[d,c] --
__global__ __launch_bounds__(256) void k_contrib(const float* __restrict__ Vt,
                                                 const float* __restrict__ att,
                                                 const int* __restrict__ sel,
                                                 const float* __restrict__ wgt,
                                                 float* __restrict__ oh,
                                                 const float* __restrict__ p_beta) {
  const int tt = blockIdx.x;                 // t-tile 0..7
  const int bh = blockIdx.y;                 // 0..31
  const int b = bh >> 3, h = bh & 7;
  const int t0 = tt * 64;
  __shared__ float Vs[64 * 64];              // [d][t']
  __shared__ float As[64 * 64];              // [d][c], pre-scaled
  const int tid = threadIdx.x;
  const int tx = tid & 15, ty = tid >> 4;
  const float beta = fminf(fmaxf(p_beta[0], 0.f), 1.f);
  const float* Vtb = Vt + (size_t)bh * DH * T_;
  float acc[4][4] = {};
  for (int m = 0; m < KTOP + 1; ++m) {
    int lag;
    float sc;
    if (m == 0) { lag = 0; sc = 1.0f - beta; }
    else {
      int li = sel[bh * KTOP + (m - 1)];
      lag = lag_of(li);
      sc = beta * wgt[bh * KTOP + (m - 1)];
    }
    const float* ab = att + ((size_t)m * BH + bh) * 4096;
#pragma unroll
    for (int j = 0; j < 16; ++j) {
      int fid = tid + 256 * j;
      int dd = fid >> 6, c = fid & 63;
      As[fid] = ab[fid] * sc;
      int tsrc = (t0 + c - lag) & 511;
      Vs[fid] = Vtb[(size_t)dd * T_ + tsrc];
    }
    __syncthreads();
#pragma unroll 8
    for (int dd = 0; dd < 64; ++dd) {
      float4 v4 = *(const float4*)(Vs + dd * 64 + 4 * ty);
      float4 a4 = *(const float4*)(As + dd * 64 + 4 * tx);
      float vv[4] = {v4.x, v4.y, v4.z, v4.w};
      float aa[4] = {a4.x, a4.y, a4.z, a4.w};
#pragma unroll
      for (int i = 0; i < 4; ++i)
#pragma unroll
        for (int j = 0; j < 4; ++j)
          acc[i][j] = fmaf(vv[i], aa[j], acc[i][j]);
    }
    __syncthreads();
  }
  float* ob = oh + (size_t)(b * T_ + t0) * D_ + h * DH;
#pragma unroll
  for (int i = 0; i < 4; ++i) {
    float4 st = make_float4(acc[i][0], acc[i][1], acc[i][2], acc[i][3]);
    *(float4*)(ob + (size_t)(4 * ty + i) * D_ + 4 * tx) = st;
  }
}

// ---------------- final projection: out = oh @ Wo + bo ------------------------
__global__ __launch_bounds__(256) void k_out_gemm(const float* __restrict__ ohT,
                                                  const float* __restrict__ Wo,
                                                  const float* __restrict__ bo,
                                                  float* __restrict__ out) {
  const int n0 = blockIdx.x * 64, m0 = blockIdx.y * 64;
  const int tx = threadIdx.x & 15, ty = threadIdx.x >> 4;
  float acc[4][4];
#pragma unroll
  for (int i = 0; i < 4; ++i)
#pragma unroll
    for (int j = 0; j < 4; ++j) acc[i][j] = bo[n0 + 4 * tx + j];
  gemm_tile(ohT, Wo, M_, D_, D_, m0, n0, acc);
#pragma unroll
  for (int i = 0; i < 4; ++i) {
    float4 st = make_float4(acc[i][0], acc[i][1], acc[i][2], acc[i][3]);
    *(float4*)(out + (size_t)(m0 + 4 * ty + i) * D_ + n0 + 4 * tx) = st;
  }
}

}  // namespace

extern "C" void kernel_launch(void* const* d_in, const int* in_sizes, int n_in,
                              void* d_out, int out_size, void* d_ws, size_t ws_size,
                              hipStream_t stream) {
  (void)in_sizes; (void)n_in; (void)out_size; (void)ws_size;
  const float* x  = (const float*)d_in[0];
  const float* Wq = (const float*)d_in[1];
  const float* bq = (const float*)d_in[2];
  const float* Wk = (const float*)d_in[3];
  const float* bk = (const float*)d_in[4];
  const float* Wv = (const float*)d_in[5];
  const float* bv = (const float*)d_in[6];
  const float* Wo = (const float*)d_in[7];
  const float* bo = (const float*)d_in[8];
  const float* p_log_tau     = (const float*)d_in[9];
  const float* p_lambda      = (const float*)d_in[10];
  const float* p_beta        = (const float*)d_in[11];
  const float* p_log_tau_lag = (const float*)d_in[12];

  float* ws = (float*)d_ws;
  const size_t SZ = (size_t)BH * T_ * DH;   // 1,048,576 floats
  float* q   = ws;
  float* k   = ws + SZ;
  float* v   = ws + 2 * SZ;
  float* vt  = ws + 3 * SZ;                 // (B,H,Dh,T)
  float* xt  = ws + 4 * SZ;                 // x^T (512 x 2048); reused later for oh^T
  float* oh  = ws + 5 * SZ;                 // out_h (B,T,D)
  float* cov = ws + 6 * SZ;                 // 65 * 32 * 4096
  float* att   = cov + (size_t)65 * BH * 4096;   // 19 * 32 * 4096
  float* score = att + (size_t)19 * BH * 4096;   // 32 * 64
  float* wgt   = score + (size_t)BH * NLAG;      // 32 * 18
  int*   sel   = (int*)(wgt + BH * KTOP);        // 32 * 18

  const dim3 blk(256);

  // 1. x^T for coalesced GEMM A-operand
  k_transpose<<<dim3(8, 32, 1), blk, 0, stream>>>(x, xt, 2048, 512);
  // 2. Q,K,V projections -> (B,H,T,Dh)
  k_qkv_gemm<<<dim3(8, 32, 3), blk, 0, stream>>>(xt, Wq, Wk, Wv, bq, bk, bv, q, k, v);
  // 3. L2 norm over time for Q and K (in place; Q,K contiguous)
  k_l2norm<<<dim3(32, 2), blk, 0, stream>>>(q);
  // 4. V -> V^T per (b,h): (Dh, T)
  k_transpose<<<dim3(1, 8, 32), blk, 0, stream>>>(v, vt, 512, 64);
  // 5. cov for lag0 + 64 lag candidates, + scores
  k_cov<<<dim3(32, 65), blk, 0, stream>>>(q, k, cov, score, p_lambda);
  // 6. top-18 lags + weights
  k_topk<<<dim3(1), dim3(64), 0, stream>>>(score, sel, wgt, p_log_tau_lag);
  // 7. row softmax -> att (19 matrices per bh)
  k_attsm<<<dim3(32, 19), blk, 0, stream>>>(cov, sel, att, p_log_tau);
  // 8. weighted contrib sum -> out_h (B,T,D)
  k_contrib<<<dim3(8, 32), blk, 0, stream>>>(vt, att, sel, wgt, oh, p_beta);
  // 9. out_h^T (reuse xt)
  k_transpose<<<dim3(8, 32, 1), blk, 0, stream>>>(oh, xt, 2048, 512);
  // 10. final projection
  k_out_gemm<<<dim3(8, 32, 1), blk, 0, stream>>>(xt, Wo, bo, (float*)d_out);
}

// Round 3
// 465.671 us; speedup vs baseline: 1.0078x; 1.0078x over previous
//
#include <hip/hip_runtime.h>
#include <math.h>

namespace {

typedef unsigned short u16;
typedef unsigned int   u32;
using bf16x8 = __attribute__((ext_vector_type(8))) short;
using f32x4  = __attribute__((ext_vector_type(4))) float;

constexpr int T_   = 512;
constexpr int BH   = 32;
constexpr int NLAG = 64;
constexpr int KTOP = 18;

__device__ __forceinline__ int lag_of(int li) { return (li < 63) ? (1 + 7 * li) : 511; }

__device__ __forceinline__ u16 bf16r(float f) {          // RNE fp32 -> bf16
  u32 u = __builtin_bit_cast(u32, f);
  u += 0x7fffu + ((u >> 16) & 1u);
  return (u16)(u >> 16);
}
__device__ __forceinline__ float bf2f(u16 h) {
  u32 u = ((u32)h) << 16;
  return __builtin_bit_cast(float, u);
}

// ---------------- x -> bf16 hi/lo split ---------------------------------------
__global__ __launch_bounds__(256) void k_prep_x(const float* __restrict__ x,
                                                u16* __restrict__ xh, u16* __restrict__ xl) {
  int i0 = (blockIdx.x * 256 + threadIdx.x) * 4;
  float4 v = *(const float4*)(x + i0);
  float vv[4] = {v.x, v.y, v.z, v.w};
  u16 h[4], lo[4];
#pragma unroll
  for (int e = 0; e < 4; ++e) { h[e] = bf16r(vv[e]); lo[e] = bf16r(vv[e] - bf2f(h[e])); }
  *(ushort4*)(xh + i0) = make_ushort4(h[0], h[1], h[2], h[3]);
  *(ushort4*)(xl + i0) = make_ushort4(lo[0], lo[1], lo[2], lo[3]);
}

// ---------------- W -> W^T bf16 hi/lo (z = q,k,v,o) ---------------------------
__global__ __launch_bounds__(256) void k_prep_w(const float* __restrict__ Wq, const float* __restrict__ Wk,
                                                const float* __restrict__ Wv, const float* __restrict__ Wo,
                                                u16* __restrict__ WTh, u16* __restrict__ WTl) {
  const int z = blockIdx.z;
  const float* W = (z == 0) ? Wq : (z == 1) ? Wk : (z == 2) ? Wv : Wo;
  u16* th = WTh + (size_t)z * 262144;
  u16* tl = WTl + (size_t)z * 262144;
  __shared__ float tile[64][65];
  const int r0 = blockIdx.y * 64, c0 = blockIdx.x * 64;
#pragma unroll
  for (int j = 0; j < 16; ++j) {
    int fid = threadIdx.x + 256 * j;
    int r = fid >> 6, c = fid & 63;
    tile[r][c] = W[(size_t)(r0 + r) * 512 + c0 + c];
  }
  __syncthreads();
#pragma unroll
  for (int j = 0; j < 16; ++j) {
    int fid = threadIdx.x + 256 * j;
    int n = fid >> 6, kk = fid & 63;
    float v = tile[kk][n];
    u16 h = bf16r(v);
    th[(size_t)(c0 + n) * 512 + r0 + kk] = h;
    tl[(size_t)(c0 + n) * 512 + r0 + kk] = bf16r(v - bf2f(h));
  }
}

// ---------------- QKV projection (MFMA). Q,K get 3-product split --------------
__global__ __launch_bounds__(256) void k_qkv(const u16* __restrict__ xh, const u16* __restrict__ xl,
                                             const u16* __restrict__ WTh, const u16* __restrict__ WTl,
                                             const float* __restrict__ bq, const float* __restrict__ bk,
                                             const float* __restrict__ bv,
                                             float* __restrict__ qo, float* __restrict__ ko, float* __restrict__ vo) {
  const int z = blockIdx.z;
  const bool split = (z < 2);                     // Q,K feed the top-k scores: fp32-grade
  const u16* Bh_ = WTh + (size_t)z * 262144;
  const u16* Bl_ = WTl + (size_t)z * 262144;
  const float* bias = (z == 0) ? bq : (z == 1) ? bk : bv;
  float* out = (z == 0) ? qo : (z == 1) ? ko : vo;
  const int n0 = blockIdx.x * 64, m0 = blockIdx.y * 64;
  const int l = threadIdx.x & 63, w = threadIdx.x >> 6;
  const int arow = m0 + 16 * w + (l & 15);
  f32x4 acc[4];
#pragma unroll
  for (int i = 0; i < 4; ++i) { float b = bias[n0 + 16 * i + (l & 15)]; acc[i] = (f32x4){b, b, b, b}; }
  for (int ks = 0; ks < 16; ++ks) {
    const int kb2 = ks * 32 + (l >> 4) * 8;
    bf16x8 A  = *(const bf16x8*)(xh + (size_t)arow * 512 + kb2);
    bf16x8 Al = {};
    if (split) Al = *(const bf16x8*)(xl + (size_t)arow * 512 + kb2);
#pragma unroll
    for (int i = 0; i < 4; ++i) {
      bf16x8 Bf = *(const bf16x8*)(Bh_ + (size_t)(n0 + 16 * i + (l & 15)) * 512 + kb2);
      acc[i] = __builtin_amdgcn_mfma_f32_16x16x32_bf16(A, Bf, acc[i], 0, 0, 0);
      if (split) {
        bf16x8 Bl2 = *(const bf16x8*)(Bl_ + (size_t)(n0 + 16 * i + (l & 15)) * 512 + kb2);
        acc[i] = __builtin_amdgcn_mfma_f32_16x16x32_bf16(A, Bl2, acc[i], 0, 0, 0);
        acc[i] = __builtin_amdgcn_mfma_f32_16x16x32_bf16(Al, Bf, acc[i], 0, 0, 0);
      }
    }
  }
#pragma unroll
  for (int i = 0; i < 4; ++i)
#pragma unroll
    for (int r = 0; r < 4; ++r) {
      int m = m0 + 16 * w + (l >> 4) * 4 + r;
      int n = n0 + 16 * i + (l & 15);
      int b_ = m >> 9, t = m & 511, h_ = n >> 6, dh = n & 63;
      out[(((size_t)(b_ * 8 + h_)) * 512 + t) * 64 + dh] = acc[i][r];
    }
}

// ---------------- L2 normalize over time, in place (Q then K) -----------------
__global__ __launch_bounds__(256) void k_l2norm(float* __restrict__ QK) {
  float* Xb = QK + (size_t)blockIdx.y * ((size_t)BH * T_ * 64) + (size_t)blockIdx.x * T_ * 64;
  const int tid = threadIdx.x;
  __shared__ float red[256];
  __shared__ float sinv[64];
  float ss = 0.f;
  for (int i = 0; i < 128; ++i) { float v = Xb[tid + 256 * i]; ss += v * v; }
  red[tid] = ss;
  __syncthreads();
  if (tid < 64) {
    float s = red[tid] + red[tid + 64] + red[tid + 128] + red[tid + 192];
    sinv[tid] = 1.0f / sqrtf(fmaxf(s, 1e-8f));
  }
  __syncthreads();
  const float inv = sinv[tid & 63];
  for (int i = 0; i < 128; ++i) Xb[tid + 256 * i] *= inv;
}

// ---------------- pack Q^T hi/lo and K hi/lo (natural layout) -----------------
__global__ __launch_bounds__(256) void k_pack_qk(const float* __restrict__ q, const float* __restrict__ k,
                                                 u16* __restrict__ QTh, u16* __restrict__ QTl,
                                                 u16* __restrict__ kh, u16* __restrict__ kl) {
  const int t0 = blockIdx.x * 64, bh = blockIdx.y;
  __shared__ float qs[64][65];
#pragma unroll
  for (int j = 0; j < 16; ++j) {
    int fid = threadIdx.x + 256 * j;
    int r = fid >> 6, c = fid & 63;
    size_t src = ((size_t)bh * 512 + t0 + r) * 64 + c;
    qs[r][c] = q[src];
    float kv = k[src];
    u16 hh = bf16r(kv);
    kh[src] = hh;
    kl[src] = bf16r(kv - bf2f(hh));
  }
  __syncthreads();
#pragma unroll
  for (int j = 0; j < 16; ++j) {
    int fid = threadIdx.x + 256 * j;
    int c = fid >> 6, tl2 = fid & 63;
    float v = qs[tl2][c];
    u16 hh = bf16r(v);
    size_t dst = ((size_t)bh * 64 + c) * 512 + t0 + tl2;
    QTh[dst] = hh;
    QTl[dst] = bf16r(v - bf2f(hh));
  }
}

// ---------------- V duplicated rows, single bf16 ------------------------------
__global__ __launch_bounds__(256) void k_v2(const float* __restrict__ v, u16* __restrict__ V2) {
  const int bh = blockIdx.y;
  const int r = threadIdx.x >> 2, ch = threadIdx.x & 3;
  const int u = blockIdx.x * 64 + r;
  const float* src = v + ((size_t)bh * 512 + (u & 511)) * 64 + ch * 16;
  u16* dh = V2 + ((size_t)bh * 1024 + u) * 64 + ch * 16;
#pragma unroll
  for (int half = 0; half < 2; ++half) {
    union { u16 s[8]; uint4 qv; } o_;
#pragma unroll
    for (int e = 0; e < 8; ++e) o_.s[e] = bf16r(src[half * 8 + e]);
    *(uint4*)(dh + half * 8) = o_.qv;
  }
}

// ---------------- cov (MFMA, 3-product hi/lo): lag-shifted K via LDS ----------
__global__ __launch_bounds__(256) void k_cov(const u16* __restrict__ kh, const u16* __restrict__ kl,
                                             const u16* __restrict__ QTh, const u16* __restrict__ QTl,
                                             float* __restrict__ cov, float* __restrict__ score,
                                             const float* __restrict__ p_lambda) {
  const int bh = blockIdx.x, li = blockIdx.y;      // li 0 => lag0; 1..64 => candidates
  const int lag = (li == 0) ? 0 : lag_of(li - 1);
  const int tid = threadIdx.x, l = tid & 63, w = tid >> 6;
  __shared__ u16 Ks[2 * 64 * 64];                  // [hi|lo] tiles, 8KB each
  __shared__ float red[256];
  char* KsB = (char*)Ks;
  const u16* khb = kh + (size_t)bh * 512 * 64;
  const u16* klb = kl + (size_t)bh * 512 * 64;
  const u16* QThb = QTh + (size_t)bh * 64 * 512;
  const u16* QTlb = QTl + (size_t)bh * 64 * 512;
  f32x4 acc[4] = {};
  const u32 dsel = (l & 1) ? 0x07060302u : 0x05040100u;
  const int dw4 = ((16 * w + (l & 15)) >> 1) * 4;   // byte offset of this lane's dword in a row
  for (int s = 0; s < 8; ++s) {
    // stage 64 t-rows of lag-shifted K hi and lo (row-granular shift: aligned)
#pragma unroll
    for (int p = 0; p < 4; ++p) {
      int fid = tid + 256 * p;                     // 0..1023
      int which = fid >> 9;                        // 0=hi, 1=lo
      int sub = fid & 511;
      int r = sub >> 3, ch = sub & 7;
      int t = (s * 64 + r - lag) & 511;
      const u16* src = which ? klb : khb;
      uint4 d = *(const uint4*)(src + (size_t)t * 64 + ch * 8);
      int ba = (r * 128 + ch * 16) ^ ((((unsigned)r >> 3) & 3) << 5);
      *(uint4*)(KsB + which * 8192 + ba) = d;
    }
    __syncthreads();
#pragma unroll
    for (int ks2 = 0; ks2 < 2; ++ks2) {
      int rbase = ks2 * 32 + (l >> 4) * 8;
      union { u32 u[4]; bf16x8 v; } Ah, Al;
#pragma unroll
      for (int jj = 0; jj < 4; ++jj) {
        int r0 = rbase + 2 * jj, r1 = r0 + 1;
        int a0 = (r0 * 128 + dw4) ^ ((((unsigned)r0 >> 3) & 3) << 5);
        int a1 = (r1 * 128 + dw4) ^ ((((unsigned)r1 >> 3) & 3) << 5);
        u32 lo_h = *(const u32*)(KsB + a0);
        u32 hi_h = *(const u32*)(KsB + a1);
        Ah.u[jj] = __builtin_amdgcn_perm(hi_h, lo_h, dsel);
        u32 lo_l = *(const u32*)(KsB + 8192 + a0);
        u32 hi_l = *(const u32*)(KsB + 8192 + a1);
        Al.u[jj] = __builtin_amdgcn_perm(hi_l, lo_l, dsel);
      }
      int kglob = s * 64 + ks2 * 32 + (l >> 4) * 8;
#pragma unroll
      for (int i = 0; i < 4; ++i) {
        bf16x8 Bh2 = *(const bf16x8*)(QThb + (size_t)(16 * i + (l & 15)) * 512 + kglob);
        bf16x8 Bl2 = *(const bf16x8*)(QTlb + (size_t)(16 * i + (l & 15)) * 512 + kglob);
        acc[i] = __builtin_amdgcn_mfma_f32_16x16x32_bf16(Ah.v, Bh2, acc[i], 0, 0, 0);
        acc[i] = __builtin_amdgcn_mfma_f32_16x16x32_bf16(Ah.v, Bl2, acc[i], 0, 0, 0);
        acc[i] = __builtin_amdgcn_mfma_f32_16x16x32_bf16(Al.v, Bh2, acc[i], 0, 0, 0);
      }
    }
    __syncthreads();
  }
  float* cb = cov + ((size_t)li * BH + bh) * 4096;
  float labs = 0.f, ldiag = 0.f;
#pragma unroll
  for (int i = 0; i < 4; ++i)
#pragma unroll
    for (int r = 0; r < 4; ++r) {
      int d = 16 * w + (l >> 4) * 4 + r;
      int c = 16 * i + (l & 15);
      float vv = acc[i][r];
      cb[(size_t)d * 64 + c] = vv;
      labs += fabsf(vv);
      if (d == c) ldiag += fabsf(vv);
    }
  red[tid] = labs;
  __syncthreads();
  for (int s2 = 128; s2 > 0; s2 >>= 1) { if (tid < s2) red[tid] += red[tid + s2]; __syncthreads(); }
  float total = red[0];
  __syncthreads();
  red[tid] = ldiag;
  __syncthreads();
  for (int s2 = 128; s2 > 0; s2 >>= 1) { if (tid < s2) red[tid] += red[tid + s2]; __syncthreads(); }
  if (tid == 0 && li > 0) {
    float lam = fminf(fmaxf(p_lambda[0], 0.f), 1.f);
    float diag = red[0];
    score[(size_t)bh * NLAG + (li - 1)] = lam * diag + (1.f - lam) * (total - diag);
  }
}

// ---------------- top-18 selection + lag-mix weights --------------------------
__global__ void k_topk(const float* __restrict__ score, int* __restrict__ sel,
                       float* __restrict__ wgt, const float* __restrict__ p_log_tau_lag) {
  const int bh = threadIdx.x;
  if (bh >= BH) return;
  const float* s = score + (size_t)bh * NLAG;
  float ts[KTOP];
  int ti[KTOP];
  unsigned long long used = 0ull;
  for (int k = 0; k < KTOP; ++k) {
    float best = -1e30f; int bi = 0;
    for (int i = 0; i < NLAG; ++i)
      if (((used >> i) & 1ull) == 0ull && s[i] > best) { best = s[i]; bi = i; }
    used |= (1ull << bi);
    ts[k] = best; ti[k] = bi;
  }
  const float tau_lag = fmaxf(expf(p_log_tau_lag[0]), 1e-4f);
  const float mx = ts[0];
  float e[KTOP]; float sum = 0.f;
  for (int k = 0; k < KTOP; ++k) { e[k] = expf((ts[k] - mx) / tau_lag); sum += e[k]; }
  const float rs = 1.0f / sum;
  for (int k = 0; k < KTOP; ++k) { sel[bh * KTOP + k] = ti[k]; wgt[bh * KTOP + k] = e[k] * rs; }
}

// ---------------- softmax + scale + transpose -> single bf16 ------------------
__global__ __launch_bounds__(256) void k_attsm(const float* __restrict__ cov, const int* __restrict__ sel,
                                               const float* __restrict__ wgt,
                                               u16* __restrict__ attT,
                                               const float* __restrict__ p_log_tau,
                                               const float* __restrict__ p_beta) {
  const int bh = blockIdx.x, m = blockIdx.y;
  const int slot = (m == 0) ? 0 : (1 + sel[bh * KTOP + m - 1]);
  const float beta = fminf(fmaxf(p_beta[0], 0.f), 1.f);
  const float smv = (m == 0) ? (1.f - beta) : (beta * wgt[bh * KTOP + m - 1]);
  const float itau = 1.f / fmaxf(expf(p_log_tau[0]), 1e-4f);
  const float* cb = cov + ((size_t)slot * BH + bh) * 4096;
  __shared__ float att_s[64][66];
  const int lane = threadIdx.x & 63, wv = threadIdx.x >> 6;
  for (int d = wv; d < 64; d += 4) {
    float v = cb[(size_t)d * 64 + lane] * itau;
    float mx = v;
#pragma unroll
    for (int off = 32; off > 0; off >>= 1) mx = fmaxf(mx, __shfl_xor(mx, off));
    float e = expf(v - mx);
    float sm2 = e;
#pragma unroll
    for (int off = 32; off > 0; off >>= 1) sm2 += __shfl_xor(sm2, off);
    att_s[d][lane] = (e / sm2) * smv;
  }
  __syncthreads();
  u16* th = attT + ((size_t)m * BH + bh) * 4096;
#pragma unroll
  for (int j = 0; j < 16; ++j) {
    int fid = threadIdx.x + 256 * j;
    int c = fid >> 6, dl2 = fid & 63;
    th[(size_t)c * 64 + dl2] = bf16r(att_s[dl2][c]);
  }
}

// ---------------- weighted contrib sum (MFMA, single bf16) --------------------
__global__ __launch_bounds__(256) void k_contrib(const u16* __restrict__ V2,
                                                 const u16* __restrict__ attT,
                                                 const int* __restrict__ sel,
                                                 u16* __restrict__ oh) {
  const int tt = blockIdx.x, bh = blockIdx.y;
  const int b_ = bh >> 3, h_ = bh & 7;
  const int t0 = tt * 64;
  const int l = threadIdx.x & 63, w = threadIdx.x >> 6;
  f32x4 acc[4] = {};
  const u16* Vb = V2 + (size_t)bh * 1024 * 64;
  for (int m = 0; m < KTOP + 1; ++m) {
    int lag = (m == 0) ? 0 : lag_of(sel[bh * KTOP + m - 1]);
    int ub = t0 + 16 * w + 512 - lag + (l & 15);
    const u16* ab = attT + ((size_t)m * BH + bh) * 4096;
#pragma unroll
    for (int ks = 0; ks < 2; ++ks) {
      int kb2 = ks * 32 + (l >> 4) * 8;
      bf16x8 A = *(const bf16x8*)(Vb + (size_t)ub * 64 + kb2);
#pragma unroll
      for (int i = 0; i < 4; ++i) {
        bf16x8 Bf = *(const bf16x8*)(ab + (size_t)(16 * i + (l & 15)) * 64 + kb2);
        acc[i] = __builtin_amdgcn_mfma_f32_16x16x32_bf16(A, Bf, acc[i], 0, 0, 0);
      }
    }
  }
#pragma unroll
  for (int i = 0; i < 4; ++i)
#pragma unroll
    for (int r = 0; r < 4; ++r) {
      int t = t0 + 16 * w + (l >> 4) * 4 + r;
      int c = 16 * i + (l & 15);
      size_t addr = ((size_t)b_ * 512 + t) * 512 + h_ * 64 + c;
      oh[addr] = bf16r(acc[i][r]);
    }
}

// ---------------- final projection (MFMA, single bf16) ------------------------
__global__ __launch_bounds__(256) void k_out(const u16* __restrict__ oh,
                                             const u16* __restrict__ WTh,
                                             const float* __restrict__ bo, float* __restrict__ out) {
  const u16* Bh_ = WTh + (size_t)3 * 262144;
  const int n0 = blockIdx.x * 64, m0 = blockIdx.y * 64;
  const int l = threadIdx.x & 63, w = threadIdx.x >> 6;
  const int arow = m0 + 16 * w + (l & 15);
  f32x4 acc[4];
#pragma unroll
  for (int i = 0; i < 4; ++i) { float b = bo[n0 + 16 * i + (l & 15)]; acc[i] = (f32x4){b, b, b, b}; }
  for (int ks = 0; ks < 16; ++ks) {
    int kb2 = ks * 32 + (l >> 4) * 8;
    bf16x8 A = *(const bf16x8*)(oh + (size_t)arow * 512 + kb2);
#pragma unroll
    for (int i = 0; i < 4; ++i) {
      bf16x8 Bf = *(const bf16x8*)(Bh_ + (size_t)(n0 + 16 * i + (l & 15)) * 512 + kb2);
      acc[i] = __builtin_amdgcn_mfma_f32_16x16x32_bf16(A, Bf, acc[i], 0, 0, 0);
    }
  }
#pragma unroll
  for (int i = 0; i < 4; ++i)
#pragma unroll
    for (int r = 0; r < 4; ++r) {
      int m = m0 + 16 * w + (l >> 4) * 4 + r;
      int n = n0 + 16 * i + (l & 15);
      out[(size_t)m * 512 + n] = acc[i][r];
    }
}

}  // namespace

extern "C" void kernel_launch(void* const* d_in, const int* in_sizes, int n_in,
                              void* d_out, int out_size, void* d_ws, size_t ws_size,
                              hipStream_t stream) {
  (void)in_sizes; (void)n_in; (void)out_size; (void)ws_size;
  const float* x  = (const float*)d_in[0];
  const float* Wq = (const float*)d_in[1];
  const float* bq = (const float*)d_in[2];
  const float* Wk = (const float*)d_in[3];
  const float* bk = (const float*)d_in[4];
  const float* Wv = (const float*)d_in[5];
  const float* bv = (const float*)d_in[6];
  const float* Wo = (const float*)d_in[7];
  const float* bo = (const float*)d_in[8];
  const float* p_log_tau     = (const float*)d_in[9];
  const float* p_lambda      = (const float*)d_in[10];
  const float* p_beta        = (const float*)d_in[11];
  const float* p_log_tau_lag = (const float*)d_in[12];

  char* ws = (char*)d_ws;
  const size_t MB = 1ull << 20;
  u16*   xh    = (u16*)(ws + 0 * MB);     // 2 MB
  u16*   xl    = (u16*)(ws + 2 * MB);     // 2 MB
  u16*   WTh   = (u16*)(ws + 4 * MB);     // 2 MB (q,k,v,o)
  u16*   WTl   = (u16*)(ws + 6 * MB);     // 2 MB
  u16*   QTh   = (u16*)(ws + 8 * MB);     // 2 MB
  u16*   QTl   = (u16*)(ws + 10 * MB);    // 2 MB
  u16*   khb   = (u16*)(ws + 12 * MB);    // 2 MB
  u16*   klb   = (u16*)(ws + 14 * MB);    // 2 MB
  u16*   V2    = (u16*)(ws + 16 * MB);    // 4 MB
  float* qf    = (float*)(ws + 20 * MB);  // 4 MB (dead after pack_qk)
  float* kf    = (float*)(ws + 24 * MB);  // 4 MB (dead after pack_qk)
  float* vf    = (float*)(ws + 28 * MB);  // 4 MB (dead after k_v2)
  u16*   attT  = (u16*)(ws + 20 * MB);    // 4.75 MB overlay on qf/kf (after pack_qk)
  u16*   oh    = (u16*)(ws + 28 * MB);    // 2 MB overlay on vf (after k_v2)
  float* cov   = (float*)(ws + 32 * MB);  // 34 MB
  float* score = (float*)(ws + 66 * MB);
  float* wgt   = (float*)(ws + 66 * MB + 16384);
  int*   sel   = (int*)(ws + 66 * MB + 32768);

  const dim3 blk(256);

  k_prep_x<<<dim3(1024), blk, 0, stream>>>(x, xh, xl);
  k_prep_w<<<dim3(8, 8, 4), blk, 0, stream>>>(Wq, Wk, Wv, Wo, WTh, WTl);
  k_qkv<<<dim3(8, 32, 3), blk, 0, stream>>>(xh, xl, WTh, WTl, bq, bk, bv, qf, kf, vf);
  k_l2norm<<<dim3(32, 2), blk, 0, stream>>>(qf);
  k_pack_qk<<<dim3(8, 32), blk, 0, stream>>>(qf, kf, QTh, QTl, khb, klb);
  k_v2<<<dim3(16, 32), blk, 0, stream>>>(vf, V2);
  k_cov<<<dim3(32, 65), blk, 0, stream>>>(khb, klb, QTh, QTl, cov, score, p_lambda);
  k_topk<<<dim3(1), dim3(64), 0, stream>>>(score, sel, wgt, p_log_tau_lag);
  k_attsm<<<dim3(32, 19), blk, 0, stream>>>(cov, sel, wgt, attT, p_log_tau, p_beta);
  k_contrib<<<dim3(8, 32), blk, 0, stream>>>(V2, attT, sel, oh);
  k_out<<<dim3(8, 32), blk, 0, stream>>>(oh, WTh, bo, (float*)d_out);
}

// Round 4
// 458.739 us; speedup vs baseline: 1.0230x; 1.0151x over previous
//
#include <hip/hip_runtime.h>
#include <math.h>

namespace {

typedef unsigned short u16;
typedef unsigned int   u32;
using bf16x8 = __attribute__((ext_vector_type(8))) short;
using f32x4  = __attribute__((ext_vector_type(4))) float;

constexpr int T_   = 512;
constexpr int BH   = 32;
constexpr int NLAG = 64;
constexpr int KTOP = 18;

__device__ __forceinline__ int lag_of(int li) { return (li < 63) ? (1 + 7 * li) : 511; }

__device__ __forceinline__ u16 bf16r(float f) {          // RNE fp32 -> bf16
  u32 u = __builtin_bit_cast(u32, f);
  u += 0x7fffu + ((u >> 16) & 1u);
  return (u16)(u >> 16);
}
__device__ __forceinline__ float bf2f(u16 h) {
  u32 u = ((u32)h) << 16;
  return __builtin_bit_cast(float, u);
}
__device__ __forceinline__ bf16x8 loadu8(const u16* p) { // 2B-aligned 16B load
  bf16x8 v;
  __builtin_memcpy(&v, p, 16);
  return v;
}

// ---------------- x -> bf16 hi/lo split ---------------------------------------
__global__ __launch_bounds__(256) void k_prep_x(const float* __restrict__ x,
                                                u16* __restrict__ xh, u16* __restrict__ xl) {
  int i0 = (blockIdx.x * 256 + threadIdx.x) * 4;
  float4 v = *(const float4*)(x + i0);
  float vv[4] = {v.x, v.y, v.z, v.w};
  u16 h[4], lo[4];
#pragma unroll
  for (int e = 0; e < 4; ++e) { h[e] = bf16r(vv[e]); lo[e] = bf16r(vv[e] - bf2f(h[e])); }
  *(ushort4*)(xh + i0) = make_ushort4(h[0], h[1], h[2], h[3]);
  *(ushort4*)(xl + i0) = make_ushort4(lo[0], lo[1], lo[2], lo[3]);
}

// ---------------- W -> W^T bf16 hi/lo (z = q,k,v,o) ---------------------------
__global__ __launch_bounds__(256) void k_prep_w(const float* __restrict__ Wq, const float* __restrict__ Wk,
                                                const float* __restrict__ Wv, const float* __restrict__ Wo,
                                                u16* __restrict__ WTh, u16* __restrict__ WTl) {
  const int z = blockIdx.z;
  const float* W = (z == 0) ? Wq : (z == 1) ? Wk : (z == 2) ? Wv : Wo;
  u16* th = WTh + (size_t)z * 262144;
  u16* tl = WTl + (size_t)z * 262144;
  __shared__ float tile[64][65];
  const int r0 = blockIdx.y * 64, c0 = blockIdx.x * 64;
#pragma unroll
  for (int j = 0; j < 16; ++j) {
    int fid = threadIdx.x + 256 * j;
    int r = fid >> 6, c = fid & 63;
    tile[r][c] = W[(size_t)(r0 + r) * 512 + c0 + c];
  }
  __syncthreads();
#pragma unroll
  for (int j = 0; j < 16; ++j) {
    int fid = threadIdx.x + 256 * j;
    int n = fid >> 6, kk = fid & 63;
    float v = tile[kk][n];
    u16 h = bf16r(v);
    th[(size_t)(c0 + n) * 512 + r0 + kk] = h;
    tl[(size_t)(c0 + n) * 512 + r0 + kk] = bf16r(v - bf2f(h));
  }
}

// ---------------- QKV projection (MFMA, 128-row m-tiles). Q,K split -----------
__global__ __launch_bounds__(256) void k_qkv(const u16* __restrict__ xh, const u16* __restrict__ xl,
                                             const u16* __restrict__ WTh, const u16* __restrict__ WTl,
                                             const float* __restrict__ bq, const float* __restrict__ bk,
                                             const float* __restrict__ bv,
                                             float* __restrict__ qo, float* __restrict__ ko, float* __restrict__ vo) {
  const int z = blockIdx.z;
  const bool split = (z < 2);                     // Q,K feed the top-k scores: fp32-grade
  const u16* Bh_ = WTh + (size_t)z * 262144;
  const u16* Bl_ = WTl + (size_t)z * 262144;
  const float* bias = (z == 0) ? bq : (z == 1) ? bk : bv;
  float* out = (z == 0) ? qo : (z == 1) ? ko : vo;
  const int n0 = blockIdx.x * 64, m0 = blockIdx.y * 128;
  const int l = threadIdx.x & 63, w = threadIdx.x >> 6;
  const int lr = l & 15, lk = (l >> 4) * 8;
  f32x4 acc[2][4];
#pragma unroll
  for (int i = 0; i < 4; ++i) {
    float b = bias[n0 + 16 * i + lr];
    acc[0][i] = (f32x4){b, b, b, b};
    acc[1][i] = acc[0][i];
  }
  for (int ks = 0; ks < 16; ++ks) {
    const int kb2 = ks * 32 + lk;
    bf16x8 Bf[4], Bl2[4];
#pragma unroll
    for (int i = 0; i < 4; ++i) {
      Bf[i] = *(const bf16x8*)(Bh_ + (size_t)(n0 + 16 * i + lr) * 512 + kb2);
      if (split) Bl2[i] = *(const bf16x8*)(Bl_ + (size_t)(n0 + 16 * i + lr) * 512 + kb2);
    }
#pragma unroll
    for (int mi = 0; mi < 2; ++mi) {
      const int arow = m0 + 64 * mi + 16 * w + lr;
      bf16x8 A  = *(const bf16x8*)(xh + (size_t)arow * 512 + kb2);
      bf16x8 Al = {};
      if (split) Al = *(const bf16x8*)(xl + (size_t)arow * 512 + kb2);
#pragma unroll
      for (int i = 0; i < 4; ++i) {
        acc[mi][i] = __builtin_amdgcn_mfma_f32_16x16x32_bf16(A, Bf[i], acc[mi][i], 0, 0, 0);
        if (split) {
          acc[mi][i] = __builtin_amdgcn_mfma_f32_16x16x32_bf16(A, Bl2[i], acc[mi][i], 0, 0, 0);
          acc[mi][i] = __builtin_amdgcn_mfma_f32_16x16x32_bf16(Al, Bf[i], acc[mi][i], 0, 0, 0);
        }
      }
    }
  }
#pragma unroll
  for (int mi = 0; mi < 2; ++mi)
#pragma unroll
    for (int i = 0; i < 4; ++i)
#pragma unroll
      for (int r = 0; r < 4; ++r) {
        int m = m0 + 64 * mi + 16 * w + (l >> 4) * 4 + r;
        int n = n0 + 16 * i + lr;
        int b_ = m >> 9, t = m & 511, h_ = n >> 6, dh = n & 63;
        out[(((size_t)(b_ * 8 + h_)) * 512 + t) * 64 + dh] = acc[mi][i][r];
      }
}

// ---------------- inverse L2 norms over time for Q and K ----------------------
__global__ __launch_bounds__(256) void k_ssq(const float* __restrict__ qf, const float* __restrict__ kf,
                                             float* __restrict__ sinv) {
  const int bh = blockIdx.x, which = blockIdx.y;
  const float* Xb = (which ? kf : qf) + (size_t)bh * T_ * 64;
  const int tid = threadIdx.x;
  __shared__ float red[256];
  float ss = 0.f;
  for (int i = 0; i < 128; ++i) { float v = Xb[tid + 256 * i]; ss += v * v; }
  red[tid] = ss;
  __syncthreads();
  if (tid < 64) {
    float s = red[tid] + red[tid + 64] + red[tid + 128] + red[tid + 192];
    sinv[which * 2048 + bh * 64 + tid] = 1.0f / sqrtf(fmaxf(s, 1e-8f));
  }
}

// ---------------- pack: Q^T hi/lo, K^T duplicated hi/lo, V duplicated ---------
__global__ __launch_bounds__(256) void k_pack(const float* __restrict__ qf, const float* __restrict__ kf,
                                              const float* __restrict__ vf, const float* __restrict__ sinv,
                                              u16* __restrict__ QTh, u16* __restrict__ QTl,
                                              u16* __restrict__ KTh, u16* __restrict__ KTl,
                                              u16* __restrict__ V2) {
  const int t0 = blockIdx.x * 64, bh = blockIdx.y;
  const int tid = threadIdx.x;
  __shared__ float tile[64][65];
  // ---- Q: normalize, transpose, hi/lo ----
#pragma unroll
  for (int j = 0; j < 16; ++j) {
    int fid = tid + 256 * j;
    int r = fid >> 6, c = fid & 63;
    tile[r][c] = qf[((size_t)bh * 512 + t0 + r) * 64 + c] * sinv[bh * 64 + c];
  }
  __syncthreads();
#pragma unroll
  for (int j = 0; j < 16; ++j) {
    int fid = tid + 256 * j;
    int c = fid >> 6, tl2 = fid & 63;
    float v = tile[tl2][c];
    u16 hh = bf16r(v);
    size_t dst = ((size_t)bh * 64 + c) * 512 + t0 + tl2;
    QTh[dst] = hh;
    QTl[dst] = bf16r(v - bf2f(hh));
  }
  __syncthreads();
  // ---- K: normalize, transpose, duplicate in t, hi/lo ----
#pragma unroll
  for (int j = 0; j < 16; ++j) {
    int fid = tid + 256 * j;
    int r = fid >> 6, c = fid & 63;
    tile[r][c] = kf[((size_t)bh * 512 + t0 + r) * 64 + c] * sinv[2048 + bh * 64 + c];
  }
  __syncthreads();
#pragma unroll
  for (int j = 0; j < 16; ++j) {
    int fid = tid + 256 * j;
    int c = fid >> 6, tl2 = fid & 63;
    float v = tile[tl2][c];
    u16 hh = bf16r(v);
    u16 ll = bf16r(v - bf2f(hh));
    size_t base = ((size_t)bh * 64 + c) * 1024 + t0 + tl2;
    KTh[base] = hh;       KTl[base] = ll;
    KTh[base + 512] = hh; KTl[base + 512] = ll;
  }
  // ---- V: duplicate rows, single bf16, natural layout ----
#pragma unroll
  for (int j = 0; j < 4; ++j) {
    int r = (tid >> 4) + 16 * j, c4 = (tid & 15) * 4;
    float4 v4 = *(const float4*)(vf + ((size_t)bh * 512 + t0 + r) * 64 + c4);
    ushort4 o = make_ushort4(bf16r(v4.x), bf16r(v4.y), bf16r(v4.z), bf16r(v4.w));
    size_t base = ((size_t)bh * 1024 + t0 + r) * 64 + c4;
    *(ushort4*)(V2 + base) = o;
    *(ushort4*)(V2 + base + 512 * 64) = o;
  }
}

// ---------------- cov (MFMA, 3-product hi/lo): one wave per (lag,bh) ----------
// KT is [bh][64][1024] with t duplicated, so the lag shift is a contiguous
// offset: A[d][k] = KT[d][k + 512 - lag]  (unaligned 16B loads, no LDS, no sync)
__global__ __launch_bounds__(256) void k_cov(const u16* __restrict__ KTh, const u16* __restrict__ KTl,
                                             const u16* __restrict__ QTh, const u16* __restrict__ QTl,
                                             float* __restrict__ cov, float* __restrict__ score,
                                             const float* __restrict__ p_lambda) {
  const int bh = blockIdx.y;
  const int li = blockIdx.x * 4 + (threadIdx.x >> 6);   // 0 => lag0; 1..64 => candidates
  if (li > 64) return;
  const int lag = (li == 0) ? 0 : lag_of(li - 1);
  const int l = threadIdx.x & 63;
  const int lr = l & 15, lk = (l >> 4) * 8;
  const u16* qh = QTh + (size_t)bh * 32768 + (size_t)lr * 512 + lk;
  const u16* ql = QTl + (size_t)bh * 32768 + (size_t)lr * 512 + lk;
  const u16* kh = KTh + (size_t)bh * 65536 + (size_t)lr * 1024 + lk + 512 - lag;
  const u16* kl = KTl + (size_t)bh * 65536 + (size_t)lr * 1024 + lk + 512 - lag;
  f32x4 acc[4][4] = {};
  for (int kk = 0; kk < 16; ++kk) {
    const int o = kk * 32;
    bf16x8 Bh2[4], Bl2[4];
#pragma unroll
    for (int ni = 0; ni < 4; ++ni) {
      Bh2[ni] = *(const bf16x8*)(qh + ni * 8192 + o);
      Bl2[ni] = *(const bf16x8*)(ql + ni * 8192 + o);
    }
#pragma unroll
    for (int mi = 0; mi < 4; ++mi) {
      bf16x8 Ah = loadu8(kh + mi * 16384 + o);
      bf16x8 Al = loadu8(kl + mi * 16384 + o);
#pragma unroll
      for (int ni = 0; ni < 4; ++ni) {
        acc[mi][ni] = __builtin_amdgcn_mfma_f32_16x16x32_bf16(Ah, Bh2[ni], acc[mi][ni], 0, 0, 0);
        acc[mi][ni] = __builtin_amdgcn_mfma_f32_16x16x32_bf16(Ah, Bl2[ni], acc[mi][ni], 0, 0, 0);
        acc[mi][ni] = __builtin_amdgcn_mfma_f32_16x16x32_bf16(Al, Bh2[ni], acc[mi][ni], 0, 0, 0);
      }
    }
  }
  float* cb = cov + ((size_t)li * BH + bh) * 4096;
  float labs = 0.f, ldiag = 0.f;
#pragma unroll
  for (int mi = 0; mi < 4; ++mi)
#pragma unroll
    for (int ni = 0; ni < 4; ++ni)
#pragma unroll
      for (int r = 0; r < 4; ++r) {
        int d = 16 * mi + (l >> 4) * 4 + r;
        int c = 16 * ni + lr;
        float vv = acc[mi][ni][r];
        cb[(size_t)d * 64 + c] = vv;
        labs += fabsf(vv);
        if (d == c) ldiag += fabsf(vv);
      }
#pragma unroll
  for (int off = 32; off > 0; off >>= 1) {
    labs += __shfl_xor(labs, off);
    ldiag += __shfl_xor(ldiag, off);
  }
  if (l == 0 && li > 0) {
    float lam = fminf(fmaxf(p_lambda[0], 0.f), 1.f);
    score[(size_t)bh * NLAG + (li - 1)] = lam * ldiag + (1.f - lam) * (labs - ldiag);
  }
}

// ---------------- top-18 selection + lag-mix weights --------------------------
__global__ void k_topk(const float* __restrict__ score, int* __restrict__ sel,
                       float* __restrict__ wgt, const float* __restrict__ p_log_tau_lag) {
  const int bh = threadIdx.x;
  if (bh >= BH) return;
  const float* s = score + (size_t)bh * NLAG;
  float ts[KTOP];
  int ti[KTOP];
  unsigned long long used = 0ull;
  for (int k = 0; k < KTOP; ++k) {
    float best = -1e30f; int bi = 0;
    for (int i = 0; i < NLAG; ++i)
      if (((used >> i) & 1ull) == 0ull && s[i] > best) { best = s[i]; bi = i; }
    used |= (1ull << bi);
    ts[k] = best; ti[k] = bi;
  }
  const float tau_lag = fmaxf(expf(p_log_tau_lag[0]), 1e-4f);
  const float mx = ts[0];
  float e[KTOP]; float sum = 0.f;
  for (int k = 0; k < KTOP; ++k) { e[k] = expf((ts[k] - mx) / tau_lag); sum += e[k]; }
  const float rs = 1.0f / sum;
  for (int k = 0; k < KTOP; ++k) { sel[bh * KTOP + k] = ti[k]; wgt[bh * KTOP + k] = e[k] * rs; }
}

// ---------------- softmax + scale + transpose -> single bf16 ------------------
__global__ __launch_bounds__(256) void k_attsm(const float* __restrict__ cov, const int* __restrict__ sel,
                                               const float* __restrict__ wgt,
                                               u16* __restrict__ attT,
                                               const float* __restrict__ p_log_tau,
                                               const float* __restrict__ p_beta) {
  const int bh = blockIdx.x, m = blockIdx.y;
  const int slot = (m == 0) ? 0 : (1 + (sel[bh * KTOP + m - 1] & 63));
  const float beta = fminf(fmaxf(p_beta[0], 0.f), 1.f);
  const float smv = (m == 0) ? (1.f - beta) : (beta * wgt[bh * KTOP + m - 1]);
  const float itau = 1.f / fmaxf(expf(p_log_tau[0]), 1e-4f);
  const float* cb = cov + ((size_t)slot * BH + bh) * 4096;
  __shared__ float att_s[64][66];
  const int lane = threadIdx.x & 63, wv = threadIdx.x >> 6;
  for (int d = wv; d < 64; d += 4) {
    float v = cb[(size_t)d * 64 + lane] * itau;
    float mx = v;
#pragma unroll
    for (int off = 32; off > 0; off >>= 1) mx = fmaxf(mx, __shfl_xor(mx, off));
    float e = expf(v - mx);
    float sm2 = e;
#pragma unroll
    for (int off = 32; off > 0; off >>= 1) sm2 += __shfl_xor(sm2, off);
    att_s[d][lane] = (e / sm2) * smv;
  }
  __syncthreads();
  u16* th = attT + ((size_t)m * BH + bh) * 4096;
#pragma unroll
  for (int j = 0; j < 16; ++j) {
    int fid = threadIdx.x + 256 * j;
    int c = fid >> 6, dl2 = fid & 63;
    th[(size_t)c * 64 + dl2] = bf16r(att_s[dl2][c]);
  }
}

// ---------------- weighted contrib sum (MFMA, single bf16) --------------------
__global__ __launch_bounds__(256) void k_contrib(const u16* __restrict__ V2,
                                                 const u16* __restrict__ attT,
                                                 const int* __restrict__ sel,
                                                 u16* __restrict__ oh) {
  const int tt = blockIdx.x, bh = blockIdx.y;
  const int b_ = bh >> 3, h_ = bh & 7;
  const int t0 = tt * 64;
  const int l = threadIdx.x & 63, w = threadIdx.x >> 6;
  f32x4 acc[4] = {};
  const u16* Vb = V2 + (size_t)bh * 1024 * 64;
  for (int m = 0; m < KTOP + 1; ++m) {
    int lag = (m == 0) ? 0 : lag_of(sel[bh * KTOP + m - 1] & 63);
    int ub = t0 + 16 * w + 512 - lag + (l & 15);
    const u16* ab = attT + ((size_t)m * BH + bh) * 4096;
#pragma unroll
    for (int ks = 0; ks < 2; ++ks) {
      int kb2 = ks * 32 + (l >> 4) * 8;
      bf16x8 A = *(const bf16x8*)(Vb + (size_t)ub * 64 + kb2);
#pragma unroll
      for (int i = 0; i < 4; ++i) {
        bf16x8 Bf = *(const bf16x8*)(ab + (size_t)(16 * i + (l & 15)) * 64 + kb2);
        acc[i] = __builtin_amdgcn_mfma_f32_16x16x32_bf16(A, Bf, acc[i], 0, 0, 0);
      }
    }
  }
#pragma unroll
  for (int i = 0; i < 4; ++i)
#pragma unroll
    for (int r = 0; r < 4; ++r) {
      int t = t0 + 16 * w + (l >> 4) * 4 + r;
      int c = 16 * i + (l & 15);
      size_t addr = ((size_t)b_ * 512 + t) * 512 + h_ * 64 + c;
      oh[addr] = bf16r(acc[i][r]);
    }
}

// ---------------- final projection (MFMA, single bf16, 128-row m-tiles) -------
__global__ __launch_bounds__(256) void k_out(const u16* __restrict__ oh,
                                             const u16* __restrict__ WTh,
                                             const float* __restrict__ bo, float* __restrict__ out) {
  const u16* Bh_ = WTh + (size_t)3 * 262144;
  const int n0 = blockIdx.x * 64, m0 = blockIdx.y * 128;
  const int l = threadIdx.x & 63, w = threadIdx.x >> 6;
  const int lr = l & 15, lk = (l >> 4) * 8;
  f32x4 acc[2][4];
#pragma unroll
  for (int i = 0; i < 4; ++i) {
    float b = bo[n0 + 16 * i + lr];
    acc[0][i] = (f32x4){b, b, b, b};
    acc[1][i] = acc[0][i];
  }
  for (int ks = 0; ks < 16; ++ks) {
    int kb2 = ks * 32 + lk;
    bf16x8 Bf[4];
#pragma unroll
    for (int i = 0; i < 4; ++i)
      Bf[i] = *(const bf16x8*)(Bh_ + (size_t)(n0 + 16 * i + lr) * 512 + kb2);
#pragma unroll
    for (int mi = 0; mi < 2; ++mi) {
      const int arow = m0 + 64 * mi + 16 * w + lr;
      bf16x8 A = *(const bf16x8*)(oh + (size_t)arow * 512 + kb2);
#pragma unroll
      for (int i = 0; i < 4; ++i)
        acc[mi][i] = __builtin_amdgcn_mfma_f32_16x16x32_bf16(A, Bf[i], acc[mi][i], 0, 0, 0);
    }
  }
#pragma unroll
  for (int mi = 0; mi < 2; ++mi)
#pragma unroll
    for (int i = 0; i < 4; ++i)
#pragma unroll
      for (int r = 0; r < 4; ++r) {
        int m = m0 + 64 * mi + 16 * w + (l >> 4) * 4 + r;
        int n = n0 + 16 * i + lr;
        out[(size_t)m * 512 + n] = acc[mi][i][r];
      }
}

}  // namespace

extern "C" void kernel_launch(void* const* d_in, const int* in_sizes, int n_in,
                              void* d_out, int out_size, void* d_ws, size_t ws_size,
                              hipStream_t stream) {
  (void)in_sizes; (void)n_in; (void)out_size; (void)ws_size;
  const float* x  = (const float*)d_in[0];
  const float* Wq = (const float*)d_in[1];
  const float* bq = (const float*)d_in[2];
  const float* Wk = (const float*)d_in[3];
  const float* bk = (const float*)d_in[4];
  const float* Wv = (const float*)d_in[5];
  const float* bv = (const float*)d_in[6];
  const float* Wo = (const float*)d_in[7];
  const float* bo = (const float*)d_in[8];
  const float* p_log_tau     = (const float*)d_in[9];
  const float* p_lambda      = (const float*)d_in[10];
  const float* p_beta        = (const float*)d_in[11];
  const float* p_log_tau_lag = (const float*)d_in[12];

  char* ws = (char*)d_ws;
  const size_t MB = 1ull << 20;
  u16*   xh    = (u16*)(ws + 0 * MB);     // 2 MB
  u16*   xl    = (u16*)(ws + 2 * MB);     // 2 MB
  u16*   WTh   = (u16*)(ws + 4 * MB);     // 2 MB (q,k,v,o)
  u16*   WTl   = (u16*)(ws + 6 * MB);     // 2 MB
  u16*   QTh   = (u16*)(ws + 8 * MB);     // 2 MB  [bh][64][512]
  u16*   QTl   = (u16*)(ws + 10 * MB);    // 2 MB
  u16*   KTh   = (u16*)(ws + 12 * MB);    // 4 MB  [bh][64][1024] t-duplicated
  u16*   KTl   = (u16*)(ws + 16 * MB);    // 4 MB
  u16*   V2    = (u16*)(ws + 20 * MB);    // 4 MB  [bh][1024][64]
  float* qf    = (float*)(ws + 24 * MB);  // 4 MB (dead after k_pack)
  float* kf    = (float*)(ws + 28 * MB);  // 4 MB (dead after k_pack)
  float* vf    = (float*)(ws + 32 * MB);  // 4 MB (dead after k_pack)
  u16*   attT  = (u16*)(ws + 24 * MB);    // 4.75 MB overlay on qf/kf (after k_pack)
  u16*   oh    = (u16*)(ws + 32 * MB);    // 2 MB overlay on vf (after k_pack)
  float* cov   = (float*)(ws + 36 * MB);  // 34 MB
  float* score = (float*)(ws + 70 * MB);          // 8 KB
  float* wgt   = (float*)(ws + 70 * MB + 16384);  // 2.3 KB
  int*   sel   = (int*)(ws + 70 * MB + 32768);    // 2.3 KB
  float* sinv  = (float*)(ws + 70 * MB + 49152);  // 16 KB [2][32][64]

  const dim3 blk(256);

  k_prep_x<<<dim3(1024), blk, 0, stream>>>(x, xh, xl);
  k_prep_w<<<dim3(8, 8, 4), blk, 0, stream>>>(Wq, Wk, Wv, Wo, WTh, WTl);
  k_qkv<<<dim3(8, 16, 3), blk, 0, stream>>>(xh, xl, WTh, WTl, bq, bk, bv, qf, kf, vf);
  k_ssq<<<dim3(32, 2), blk, 0, stream>>>(qf, kf, sinv);
  k_pack<<<dim3(8, 32), blk, 0, stream>>>(qf, kf, vf, sinv, QTh, QTl, KTh, KTl, V2);
  k_cov<<<dim3(17, 32), blk, 0, stream>>>(KTh, KTl, QTh, QTl, cov, score, p_lambda);
  k_topk<<<dim3(1), dim3(64), 0, stream>>>(score, sel, wgt, p_log_tau_lag);
  k_attsm<<<dim3(32, 19), blk, 0, stream>>>(cov, sel, wgt, attT, p_log_tau, p_beta);
  k_contrib<<<dim3(8, 32), blk, 0, stream>>>(V2, attT, sel, oh);
  k_out<<<dim3(8, 16), blk, 0, stream>>>(oh, WTh, bo, (float*)d_out);
}

// Round 5
// 403.312 us; speedup vs baseline: 1.1636x; 1.1374x over previous
//
#include <hip/hip_runtime.h>
#include <math.h>

namespace {

typedef unsigned short u16;
typedef unsigned int   u32;
using bf16x8 = __attribute__((ext_vector_type(8))) short;
using f32x4  = __attribute__((ext_vector_type(4))) float;

constexpr int T_   = 512;
constexpr int BH   = 32;
constexpr int NLAG = 64;
constexpr int KTOP = 18;

__device__ __forceinline__ int lag_of(int li) { return (li < 63) ? (1 + 7 * li) : 511; }

__device__ __forceinline__ u16 bf16r(float f) {          // RNE fp32 -> bf16
  u32 u = __builtin_bit_cast(u32, f);
  u += 0x7fffu + ((u >> 16) & 1u);
  return (u16)(u >> 16);
}
__device__ __forceinline__ float bf2f(u16 h) {
  u32 u = ((u32)h) << 16;
  return __builtin_bit_cast(float, u);
}

// Aligned 16B load at even element pe, returning elements [odd .. odd+7].
// odd is wave-uniform; realignment is 4 v_alignbit (VALU is idle anyway).
__device__ __forceinline__ bf16x8 load_shift8(const u16* pe, int odd) {
  uint4 a = *(const uint4*)(pe);
  union { u32 u[4]; bf16x8 v; } r;
  if (odd) {
    u32 b = *(const u32*)(pe + 8);
    r.u[0] = __builtin_amdgcn_alignbit(a.y, a.x, 16);
    r.u[1] = __builtin_amdgcn_alignbit(a.z, a.y, 16);
    r.u[2] = __builtin_amdgcn_alignbit(a.w, a.z, 16);
    r.u[3] = __builtin_amdgcn_alignbit(b,   a.w, 16);
  } else {
    r.u[0] = a.x; r.u[1] = a.y; r.u[2] = a.z; r.u[3] = a.w;
  }
  return r.v;
}

// ---------------- x -> bf16 hi/lo split ---------------------------------------
__global__ __launch_bounds__(256) void k_prep_x(const float* __restrict__ x,
                                                u16* __restrict__ xh, u16* __restrict__ xl) {
  int i0 = (blockIdx.x * 256 + threadIdx.x) * 4;
  float4 v = *(const float4*)(x + i0);
  float vv[4] = {v.x, v.y, v.z, v.w};
  u16 h[4], lo[4];
#pragma unroll
  for (int e = 0; e < 4; ++e) { h[e] = bf16r(vv[e]); lo[e] = bf16r(vv[e] - bf2f(h[e])); }
  *(ushort4*)(xh + i0) = make_ushort4(h[0], h[1], h[2], h[3]);
  *(ushort4*)(xl + i0) = make_ushort4(lo[0], lo[1], lo[2], lo[3]);
}

// ---------------- W -> W^T bf16 hi/lo (z = q,k,v,o) ---------------------------
__global__ __launch_bounds__(256) void k_prep_w(const float* __restrict__ Wq, const float* __restrict__ Wk,
                                                const float* __restrict__ Wv, const float* __restrict__ Wo,
                                                u16* __restrict__ WTh, u16* __restrict__ WTl) {
  const int z = blockIdx.z;
  const float* W = (z == 0) ? Wq : (z == 1) ? Wk : (z == 2) ? Wv : Wo;
  u16* th = WTh + (size_t)z * 262144;
  u16* tl = WTl + (size_t)z * 262144;
  __shared__ float tile[64][65];
  const int r0 = blockIdx.y * 64, c0 = blockIdx.x * 64;
#pragma unroll
  for (int j = 0; j < 16; ++j) {
    int fid = threadIdx.x + 256 * j;
    int r = fid >> 6, c = fid & 63;
    tile[r][c] = W[(size_t)(r0 + r) * 512 + c0 + c];
  }
  __syncthreads();
#pragma unroll
  for (int j = 0; j < 16; ++j) {
    int fid = threadIdx.x + 256 * j;
    int n = fid >> 6, kk = fid & 63;
    float v = tile[kk][n];
    u16 h = bf16r(v);
    th[(size_t)(c0 + n) * 512 + r0 + kk] = h;
    tl[(size_t)(c0 + n) * 512 + r0 + kk] = bf16r(v - bf2f(h));
  }
}

// ---------------- QKV projection (MFMA, 64-row m-tiles). Q,K split ------------
__global__ __launch_bounds__(256) void k_qkv(const u16* __restrict__ xh, const u16* __restrict__ xl,
                                             const u16* __restrict__ WTh, const u16* __restrict__ WTl,
                                             const float* __restrict__ bq, const float* __restrict__ bk,
                                             const float* __restrict__ bv,
                                             float* __restrict__ qo, float* __restrict__ ko, float* __restrict__ vo) {
  const int z = blockIdx.z;
  const bool split = (z < 2);                     // Q,K feed the top-k scores: fp32-grade
  const u16* Bh_ = WTh + (size_t)z * 262144;
  const u16* Bl_ = WTl + (size_t)z * 262144;
  const float* bias = (z == 0) ? bq : (z == 1) ? bk : bv;
  float* out = (z == 0) ? qo : (z == 1) ? ko : vo;
  const int n0 = blockIdx.x * 64, m0 = blockIdx.y * 64;
  const int l = threadIdx.x & 63, w = threadIdx.x >> 6;
  const int lr = l & 15, lk = (l >> 4) * 8;
  const int arow = m0 + 16 * w + lr;
  f32x4 acc[4];
#pragma unroll
  for (int i = 0; i < 4; ++i) { float b = bias[n0 + 16 * i + lr]; acc[i] = (f32x4){b, b, b, b}; }
  for (int ks = 0; ks < 16; ++ks) {
    const int kb2 = ks * 32 + lk;
    bf16x8 A  = *(const bf16x8*)(xh + (size_t)arow * 512 + kb2);
    bf16x8 Al = {};
    if (split) Al = *(const bf16x8*)(xl + (size_t)arow * 512 + kb2);
#pragma unroll
    for (int i = 0; i < 4; ++i) {
      bf16x8 Bf = *(const bf16x8*)(Bh_ + (size_t)(n0 + 16 * i + lr) * 512 + kb2);
      acc[i] = __builtin_amdgcn_mfma_f32_16x16x32_bf16(A, Bf, acc[i], 0, 0, 0);
      if (split) {
        bf16x8 Bl2 = *(const bf16x8*)(Bl_ + (size_t)(n0 + 16 * i + lr) * 512 + kb2);
        acc[i] = __builtin_amdgcn_mfma_f32_16x16x32_bf16(A, Bl2, acc[i], 0, 0, 0);
        acc[i] = __builtin_amdgcn_mfma_f32_16x16x32_bf16(Al, Bf, acc[i], 0, 0, 0);
      }
    }
  }
#pragma unroll
  for (int i = 0; i < 4; ++i)
#pragma unroll
    for (int r = 0; r < 4; ++r) {
      int m = m0 + 16 * w + (l >> 4) * 4 + r;
      int n = n0 + 16 * i + lr;
      int b_ = m >> 9, t = m & 511, h_ = n >> 6, dh = n & 63;
      out[(((size_t)(b_ * 8 + h_)) * 512 + t) * 64 + dh] = acc[i][r];
    }
}

// ---------------- inverse L2 norms over time for Q and K ----------------------
__global__ __launch_bounds__(256) void k_ssq(const float* __restrict__ qf, const float* __restrict__ kf,
                                             float* __restrict__ sinv) {
  const int bh = blockIdx.x, which = blockIdx.y;
  const float* Xb = (which ? kf : qf) + (size_t)bh * T_ * 64;
  const int tid = threadIdx.x;
  __shared__ float red[256];
  float ss = 0.f;
  for (int i = 0; i < 128; ++i) { float v = Xb[tid + 256 * i]; ss += v * v; }
  red[tid] = ss;
  __syncthreads();
  if (tid < 64) {
    float s = red[tid] + red[tid + 64] + red[tid + 128] + red[tid + 192];
    sinv[which * 2048 + bh * 64 + tid] = 1.0f / sqrtf(fmaxf(s, 1e-8f));
  }
}

// ---------------- pack: Q^T hi/lo, K^T duplicated hi/lo, V duplicated ---------
__global__ __launch_bounds__(256) void k_pack(const float* __restrict__ qf, const float* __restrict__ kf,
                                              const float* __restrict__ vf, const float* __restrict__ sinv,
                                              u16* __restrict__ QTh, u16* __restrict__ QTl,
                                              u16* __restrict__ KTh, u16* __restrict__ KTl,
                                              u16* __restrict__ V2) {
  const int t0 = blockIdx.x * 64, bh = blockIdx.y;
  const int tid = threadIdx.x;
  __shared__ float tile[64][65];
  // ---- Q: normalize, transpose, hi/lo ----
#pragma unroll
  for (int j = 0; j < 16; ++j) {
    int fid = tid + 256 * j;
    int r = fid >> 6, c = fid & 63;
    tile[r][c] = qf[((size_t)bh * 512 + t0 + r) * 64 + c] * sinv[bh * 64 + c];
  }
  __syncthreads();
#pragma unroll
  for (int j = 0; j < 16; ++j) {
    int fid = tid + 256 * j;
    int c = fid >> 6, tl2 = fid & 63;
    float v = tile[tl2][c];
    u16 hh = bf16r(v);
    size_t dst = ((size_t)bh * 64 + c) * 512 + t0 + tl2;
    QTh[dst] = hh;
    QTl[dst] = bf16r(v - bf2f(hh));
  }
  __syncthreads();
  // ---- K: normalize, transpose, duplicate in t, hi/lo ----
#pragma unroll
  for (int j = 0; j < 16; ++j) {
    int fid = tid + 256 * j;
    int r = fid >> 6, c = fid & 63;
    tile[r][c] = kf[((size_t)bh * 512 + t0 + r) * 64 + c] * sinv[2048 + bh * 64 + c];
  }
  __syncthreads();
#pragma unroll
  for (int j = 0; j < 16; ++j) {
    int fid = tid + 256 * j;
    int c = fid >> 6, tl2 = fid & 63;
    float v = tile[tl2][c];
    u16 hh = bf16r(v);
    u16 ll = bf16r(v - bf2f(hh));
    size_t base = ((size_t)bh * 64 + c) * 1024 + t0 + tl2;
    KTh[base] = hh;       KTl[base] = ll;
    KTh[base + 512] = hh; KTl[base + 512] = ll;
  }
  // ---- V: duplicate rows, single bf16, natural layout ----
#pragma unroll
  for (int j = 0; j < 4; ++j) {
    int r = (tid >> 4) + 16 * j, c4 = (tid & 15) * 4;
    float4 v4 = *(const float4*)(vf + ((size_t)bh * 512 + t0 + r) * 64 + c4);
    ushort4 o = make_ushort4(bf16r(v4.x), bf16r(v4.y), bf16r(v4.z), bf16r(v4.w));
    size_t base = ((size_t)bh * 1024 + t0 + r) * 64 + c4;
    *(ushort4*)(V2 + base) = o;
    *(ushort4*)(V2 + base + 512 * 64) = o;
  }
}

// ---------------- cov (MFMA, 3-product hi/lo), 4-way k-split per block --------
// KT is [bh][64][1024] t-duplicated: lag shift = contiguous offset. Aligned
// dwordx4 loads always; odd shifts realigned in-register via v_alignbit.
// 4 waves each do K=128, then 2-phase LDS reduce (32KB).
__global__ __launch_bounds__(256, 4) void k_cov(const u16* __restrict__ KTh, const u16* __restrict__ KTl,
                                                const u16* __restrict__ QTh, const u16* __restrict__ QTl,
                                                float* __restrict__ cov, float* __restrict__ score,
                                                const float* __restrict__ p_lambda) {
  const int li = blockIdx.x;                      // 0 => lag0; 1..64 => candidates
  const int bh = blockIdx.y;
  const int lag = (li == 0) ? 0 : lag_of(li - 1);
  const int tid = threadIdx.x, l = tid & 63, w = tid >> 6;
  const int lr = l & 15, lk = (l >> 4) * 8;
  __shared__ f32x4 lred[2][1024];                 // 32 KB
  const int shift = 512 - lag;                    // 1..512
  const int sbase = shift & ~1;
  const int odd = shift & 1;
  const u16* qh = QTh + (size_t)bh * 32768 + (size_t)lr * 512 + w * 128 + lk;
  const u16* ql = QTl + (size_t)bh * 32768 + (size_t)lr * 512 + w * 128 + lk;
  const u16* kh = KTh + (size_t)bh * 65536 + (size_t)lr * 1024 + w * 128 + lk + sbase;
  const u16* kl = KTl + (size_t)bh * 65536 + (size_t)lr * 1024 + w * 128 + lk + sbase;
  f32x4 acc[4][4] = {};
#pragma unroll
  for (int kk = 0; kk < 4; ++kk) {
    const int o = kk * 32;
    bf16x8 Bh2[4], Bl2[4];
#pragma unroll
    for (int ni = 0; ni < 4; ++ni) {
      Bh2[ni] = *(const bf16x8*)(qh + ni * 8192 + o);
      Bl2[ni] = *(const bf16x8*)(ql + ni * 8192 + o);
    }
#pragma unroll
    for (int mi = 0; mi < 4; ++mi) {
      bf16x8 Ah = load_shift8(kh + mi * 16384 + o, odd);
      bf16x8 Al = load_shift8(kl + mi * 16384 + o, odd);
#pragma unroll
      for (int ni = 0; ni < 4; ++ni) {
        acc[mi][ni] = __builtin_amdgcn_mfma_f32_16x16x32_bf16(Ah, Bh2[ni], acc[mi][ni], 0, 0, 0);
        acc[mi][ni] = __builtin_amdgcn_mfma_f32_16x16x32_bf16(Ah, Bl2[ni], acc[mi][ni], 0, 0, 0);
        acc[mi][ni] = __builtin_amdgcn_mfma_f32_16x16x32_bf16(Al, Bh2[ni], acc[mi][ni], 0, 0, 0);
      }
    }
  }
  // 2-phase cross-wave reduction
  if (w >= 2) {
#pragma unroll
    for (int mi = 0; mi < 4; ++mi)
#pragma unroll
      for (int ni = 0; ni < 4; ++ni) lred[w - 2][(mi * 4 + ni) * 64 + l] = acc[mi][ni];
  }
  __syncthreads();
  if (w < 2) {
#pragma unroll
    for (int mi = 0; mi < 4; ++mi)
#pragma unroll
      for (int ni = 0; ni < 4; ++ni) acc[mi][ni] += lred[w][(mi * 4 + ni) * 64 + l];
  }
  __syncthreads();
  if (w == 1) {
#pragma unroll
    for (int mi = 0; mi < 4; ++mi)
#pragma unroll
      for (int ni = 0; ni < 4; ++ni) lred[0][(mi * 4 + ni) * 64 + l] = acc[mi][ni];
  }
  __syncthreads();
  if (w == 0) {
#pragma unroll
    for (int mi = 0; mi < 4; ++mi)
#pragma unroll
      for (int ni = 0; ni < 4; ++ni) acc[mi][ni] += lred[0][(mi * 4 + ni) * 64 + l];
    float* cb = cov + ((size_t)li * BH + bh) * 4096;
    float labs = 0.f, ldiag = 0.f;
#pragma unroll
    for (int mi = 0; mi < 4; ++mi)
#pragma unroll
      for (int ni = 0; ni < 4; ++ni)
#pragma unroll
        for (int r = 0; r < 4; ++r) {
          int d = 16 * mi + (l >> 4) * 4 + r;
          int c = 16 * ni + lr;
          float vv = acc[mi][ni][r];
          cb[(size_t)d * 64 + c] = vv;
          labs += fabsf(vv);
          if (d == c) ldiag += fabsf(vv);
        }
#pragma unroll
    for (int off = 32; off > 0; off >>= 1) {
      labs += __shfl_xor(labs, off);
      ldiag += __shfl_xor(ldiag, off);
    }
    if (l == 0 && li > 0) {
      float lam = fminf(fmaxf(p_lambda[0], 0.f), 1.f);
      score[(size_t)bh * NLAG + (li - 1)] = lam * ldiag + (1.f - lam) * (labs - ldiag);
    }
  }
}

// ---------------- top-18 selection + lag-mix weights --------------------------
__global__ void k_topk(const float* __restrict__ score, int* __restrict__ sel,
                       float* __restrict__ wgt, const float* __restrict__ p_log_tau_lag) {
  const int bh = threadIdx.x;
  if (bh >= BH) return;
  const float* s = score + (size_t)bh * NLAG;
  float ts[KTOP];
  int ti[KTOP];
  unsigned long long used = 0ull;
  for (int k = 0; k < KTOP; ++k) {
    float best = -1e30f; int bi = 0;
    for (int i = 0; i < NLAG; ++i)
      if (((used >> i) & 1ull) == 0ull && s[i] > best) { best = s[i]; bi = i; }
    used |= (1ull << bi);
    ts[k] = best; ti[k] = bi;
  }
  const float tau_lag = fmaxf(expf(p_log_tau_lag[0]), 1e-4f);
  const float mx = ts[0];
  float e[KTOP]; float sum = 0.f;
  for (int k = 0; k < KTOP; ++k) { e[k] = expf((ts[k] - mx) / tau_lag); sum += e[k]; }
  const float rs = 1.0f / sum;
  for (int k = 0; k < KTOP; ++k) { sel[bh * KTOP + k] = ti[k]; wgt[bh * KTOP + k] = e[k] * rs; }
}

// ---------------- softmax + scale + transpose -> single bf16 ------------------
__global__ __launch_bounds__(256) void k_attsm(const float* __restrict__ cov, const int* __restrict__ sel,
                                               const float* __restrict__ wgt,
                                               u16* __restrict__ attT,
                                               const float* __restrict__ p_log_tau,
                                               const float* __restrict__ p_beta) {
  const int bh = blockIdx.x, m = blockIdx.y;
  const int slot = (m == 0) ? 0 : (1 + (sel[bh * KTOP + m - 1] & 63));
  const float beta = fminf(fmaxf(p_beta[0], 0.f), 1.f);
  const float smv = (m == 0) ? (1.f - beta) : (beta * wgt[bh * KTOP + m - 1]);
  const float itau = 1.f / fmaxf(expf(p_log_tau[0]), 1e-4f);
  const float* cb = cov + ((size_t)slot * BH + bh) * 4096;
  __shared__ float att_s[64][66];
  const int lane = threadIdx.x & 63, wv = threadIdx.x >> 6;
  for (int d = wv; d < 64; d += 4) {
    float v = cb[(size_t)d * 64 + lane] * itau;
    float mx = v;
#pragma unroll
    for (int off = 32; off > 0; off >>= 1) mx = fmaxf(mx, __shfl_xor(mx, off));
    float e = expf(v - mx);
    float sm2 = e;
#pragma unroll
    for (int off = 32; off > 0; off >>= 1) sm2 += __shfl_xor(sm2, off);
    att_s[d][lane] = (e / sm2) * smv;
  }
  __syncthreads();
  u16* th = attT + ((size_t)m * BH + bh) * 4096;
#pragma unroll
  for (int j = 0; j < 16; ++j) {
    int fid = threadIdx.x + 256 * j;
    int c = fid >> 6, dl2 = fid & 63;
    th[(size_t)c * 64 + dl2] = bf16r(att_s[dl2][c]);
  }
}

// ---------------- weighted contrib sum: m-split across waves + LDS reduce -----
__global__ __launch_bounds__(256) void k_contrib(const u16* __restrict__ V2,
                                                 const u16* __restrict__ attT,
                                                 const int* __restrict__ sel,
                                                 u16* __restrict__ oh) {
  const int tt = blockIdx.x;                 // 32-row t-tiles: 0..15
  const int bh = blockIdx.y;
  const int b_ = bh >> 3, h_ = bh & 7;
  const int t0 = tt * 32;
  const int tid = threadIdx.x, l = tid & 63, w = tid >> 6;
  const int lr = l & 15, lk = (l >> 4) * 8;
  __shared__ f32x4 lred[2][512];             // 16 KB
  f32x4 acc[2][4] = {};
  const u16* Vb = V2 + (size_t)bh * 65536;
  const int mstart[5] = {0, 5, 10, 15, 19};
  for (int m = mstart[w]; m < mstart[w + 1]; ++m) {
    const int lag = (m == 0) ? 0 : lag_of(sel[bh * KTOP + m - 1] & 63);
    const u16* ab = attT + ((size_t)m * BH + bh) * 4096;
#pragma unroll
    for (int ks = 0; ks < 2; ++ks) {
      const int kb2 = ks * 32 + lk;
      bf16x8 Bf[4];
#pragma unroll
      for (int ni = 0; ni < 4; ++ni) Bf[ni] = *(const bf16x8*)(ab + (size_t)(16 * ni + lr) * 64 + kb2);
#pragma unroll
      for (int mi = 0; mi < 2; ++mi) {
        const int ub = t0 + 16 * mi + 512 - lag + lr;
        bf16x8 A = *(const bf16x8*)(Vb + (size_t)ub * 64 + kb2);
#pragma unroll
        for (int ni = 0; ni < 4; ++ni)
          acc[mi][ni] = __builtin_amdgcn_mfma_f32_16x16x32_bf16(A, Bf[ni], acc[mi][ni], 0, 0, 0);
      }
    }
  }
  if (w >= 2) {
#pragma unroll
    for (int mi = 0; mi < 2; ++mi)
#pragma unroll
      for (int ni = 0; ni < 4; ++ni) lred[w - 2][(mi * 4 + ni) * 64 + l] = acc[mi][ni];
  }
  __syncthreads();
  if (w < 2) {
#pragma unroll
    for (int mi = 0; mi < 2; ++mi)
#pragma unroll
      for (int ni = 0; ni < 4; ++ni) acc[mi][ni] += lred[w][(mi * 4 + ni) * 64 + l];
  }
  __syncthreads();
  if (w == 1) {
#pragma unroll
    for (int mi = 0; mi < 2; ++mi)
#pragma unroll
      for (int ni = 0; ni < 4; ++ni) lred[0][(mi * 4 + ni) * 64 + l] = acc[mi][ni];
  }
  __syncthreads();
  if (w == 0) {
#pragma unroll
    for (int mi = 0; mi < 2; ++mi)
#pragma unroll
      for (int ni = 0; ni < 4; ++ni) {
        acc[mi][ni] += lred[0][(mi * 4 + ni) * 64 + l];
#pragma unroll
        for (int r = 0; r < 4; ++r) {
          int t = t0 + 16 * mi + (l >> 4) * 4 + r;
          int c = 16 * ni + lr;
          oh[((size_t)b_ * 512 + t) * 512 + h_ * 64 + c] = bf16r(acc[mi][ni][r]);
        }
      }
  }
}

// ---------------- final projection (MFMA, single bf16, 64-row m-tiles) --------
__global__ __launch_bounds__(256) void k_out(const u16* __restrict__ oh,
                                             const u16* __restrict__ WTh,
                                             const float* __restrict__ bo, float* __restrict__ out) {
  const u16* Bh_ = WTh + (size_t)3 * 262144;
  const int n0 = blockIdx.x * 64, m0 = blockIdx.y * 64;
  const int l = threadIdx.x & 63, w = threadIdx.x >> 6;
  const int lr = l & 15, lk = (l >> 4) * 8;
  const int arow = m0 + 16 * w + lr;
  f32x4 acc[4];
#pragma unroll
  for (int i = 0; i < 4; ++i) { float b = bo[n0 + 16 * i + lr]; acc[i] = (f32x4){b, b, b, b}; }
  for (int ks = 0; ks < 16; ++ks) {
    int kb2 = ks * 32 + lk;
    bf16x8 A = *(const bf16x8*)(oh + (size_t)arow * 512 + kb2);
#pragma unroll
    for (int i = 0; i < 4; ++i) {
      bf16x8 Bf = *(const bf16x8*)(Bh_ + (size_t)(n0 + 16 * i + lr) * 512 + kb2);
      acc[i] = __builtin_amdgcn_mfma_f32_16x16x32_bf16(A, Bf, acc[i], 0, 0, 0);
    }
  }
#pragma unroll
  for (int i = 0; i < 4; ++i)
#pragma unroll
    for (int r = 0; r < 4; ++r) {
      int m = m0 + 16 * w + (l >> 4) * 4 + r;
      int n = n0 + 16 * i + lr;
      out[(size_t)m * 512 + n] = acc[i][r];
    }
}

}  // namespace

extern "C" void kernel_launch(void* const* d_in, const int* in_sizes, int n_in,
                              void* d_out, int out_size, void* d_ws, size_t ws_size,
                              hipStream_t stream) {
  (void)in_sizes; (void)n_in; (void)out_size; (void)ws_size;
  const float* x  = (const float*)d_in[0];
  const float* Wq = (const float*)d_in[1];
  const float* bq = (const float*)d_in[2];
  const float* Wk = (const float*)d_in[3];
  const float* bk = (const float*)d_in[4];
  const float* Wv = (const float*)d_in[5];
  const float* bv = (const float*)d_in[6];
  const float* Wo = (const float*)d_in[7];
  const float* bo = (const float*)d_in[8];
  const float* p_log_tau     = (const float*)d_in[9];
  const float* p_lambda      = (const float*)d_in[10];
  const float* p_beta        = (const float*)d_in[11];
  const float* p_log_tau_lag = (const float*)d_in[12];

  char* ws = (char*)d_ws;
  const size_t MB = 1ull << 20;
  u16*   xh    = (u16*)(ws + 0 * MB);     // 2 MB
  u16*   xl    = (u16*)(ws + 2 * MB);     // 2 MB
  u16*   WTh   = (u16*)(ws + 4 * MB);     // 2 MB (q,k,v,o)
  u16*   WTl   = (u16*)(ws + 6 * MB);     // 2 MB
  u16*   QTh   = (u16*)(ws + 8 * MB);     // 2 MB  [bh][64][512]
  u16*   QTl   = (u16*)(ws + 10 * MB);    // 2 MB
  u16*   KTh   = (u16*)(ws + 12 * MB);    // 4 MB  [bh][64][1024] t-duplicated
  u16*   KTl   = (u16*)(ws + 16 * MB);    // 4 MB
  u16*   V2    = (u16*)(ws + 20 * MB);    // 4 MB  [bh][1024][64]
  float* qf    = (float*)(ws + 24 * MB);  // 4 MB (dead after k_pack)
  float* kf    = (float*)(ws + 28 * MB);  // 4 MB (dead after k_pack)
  float* vf    = (float*)(ws + 32 * MB);  // 4 MB (dead after k_pack)
  u16*   attT  = (u16*)(ws + 24 * MB);    // 4.75 MB overlay on qf/kf (after k_pack)
  u16*   oh    = (u16*)(ws + 32 * MB);    // 2 MB overlay on vf (after k_pack)
  float* cov   = (float*)(ws + 36 * MB);  // 34 MB
  float* score = (float*)(ws + 70 * MB);          // 8 KB
  float* wgt   = (float*)(ws + 70 * MB + 16384);  // 2.3 KB
  int*   sel   = (int*)(ws + 70 * MB + 32768);    // 2.3 KB
  float* sinv  = (float*)(ws + 70 * MB + 49152);  // 16 KB [2][32][64]

  const dim3 blk(256);

  k_prep_x<<<dim3(1024), blk, 0, stream>>>(x, xh, xl);
  k_prep_w<<<dim3(8, 8, 4), blk, 0, stream>>>(Wq, Wk, Wv, Wo, WTh, WTl);
  k_qkv<<<dim3(8, 32, 3), blk, 0, stream>>>(xh, xl, WTh, WTl, bq, bk, bv, qf, kf, vf);
  k_ssq<<<dim3(32, 2), blk, 0, stream>>>(qf, kf, sinv);
  k_pack<<<dim3(8, 32), blk, 0, stream>>>(qf, kf, vf, sinv, QTh, QTl, KTh, KTl, V2);
  k_cov<<<dim3(65, 32), blk, 0, stream>>>(KTh, KTl, QTh, QTl, cov, score, p_lambda);
  k_topk<<<dim3(1), dim3(64), 0, stream>>>(score, sel, wgt, p_log_tau_lag);
  k_attsm<<<dim3(32, 19), blk, 0, stream>>>(cov, sel, wgt, attT, p_log_tau, p_beta);
  k_contrib<<<dim3(16, 32), blk, 0, stream>>>(V2, attT, sel, oh);
  k_out<<<dim3(8, 32), blk, 0, stream>>>(oh, WTh, bo, (float*)d_out);
}

// Round 6
// 301.381 us; speedup vs baseline: 1.5572x; 1.3382x over previous
//
#include <hip/hip_runtime.h>
#include <math.h>

namespace {

typedef unsigned short u16;
typedef unsigned int   u32;
using bf16x8 = __attribute__((ext_vector_type(8))) short;
using f32x4  = __attribute__((ext_vector_type(4))) float;

constexpr int T_   = 512;
constexpr int BH   = 32;
constexpr int NLAG = 64;
constexpr int KTOP = 18;

__device__ __forceinline__ int lag_of(int li) { return (li < 63) ? (1 + 7 * li) : 511; }

__device__ __forceinline__ u16 bf16r(float f) {          // RNE fp32 -> bf16
  u32 u = __builtin_bit_cast(u32, f);
  u += 0x7fffu + ((u >> 16) & 1u);
  return (u16)(u >> 16);
}
__device__ __forceinline__ float bf2f(u16 h) {
  u32 u = ((u32)h) << 16;
  return __builtin_bit_cast(float, u);
}

// Aligned 16B load at even element pe, returning elements [odd .. odd+7].
// odd is wave-uniform; realignment is 4 v_alignbit (VALU is idle anyway).
__device__ __forceinline__ bf16x8 load_shift8(const u16* pe, int odd) {
  uint4 a = *(const uint4*)(pe);
  union { u32 u[4]; bf16x8 v; } r;
  if (odd) {
    u32 b = *(const u32*)(pe + 8);
    r.u[0] = __builtin_amdgcn_alignbit(a.y, a.x, 16);
    r.u[1] = __builtin_amdgcn_alignbit(a.z, a.y, 16);
    r.u[2] = __builtin_amdgcn_alignbit(a.w, a.z, 16);
    r.u[3] = __builtin_amdgcn_alignbit(b,   a.w, 16);
  } else {
    r.u[0] = a.x; r.u[1] = a.y; r.u[2] = a.z; r.u[3] = a.w;
  }
  return r.v;
}

// ---------------- x -> bf16 hi/lo split ---------------------------------------
__global__ __launch_bounds__(256) void k_prep_x(const float* __restrict__ x,
                                                u16* __restrict__ xh, u16* __restrict__ xl) {
  int i0 = (blockIdx.x * 256 + threadIdx.x) * 4;
  float4 v = *(const float4*)(x + i0);
  float vv[4] = {v.x, v.y, v.z, v.w};
  u16 h[4], lo[4];
#pragma unroll
  for (int e = 0; e < 4; ++e) { h[e] = bf16r(vv[e]); lo[e] = bf16r(vv[e] - bf2f(h[e])); }
  *(ushort4*)(xh + i0) = make_ushort4(h[0], h[1], h[2], h[3]);
  *(ushort4*)(xl + i0) = make_ushort4(lo[0], lo[1], lo[2], lo[3]);
}

// ---------------- W -> W^T bf16 hi/lo (z = q,k,v,o) ---------------------------
__global__ __launch_bounds__(256) void k_prep_w(const float* __restrict__ Wq, const float* __restrict__ Wk,
                                                const float* __restrict__ Wv, const float* __restrict__ Wo,
                                                u16* __restrict__ WTh, u16* __restrict__ WTl) {
  const int z = blockIdx.z;
  const float* W = (z == 0) ? Wq : (z == 1) ? Wk : (z == 2) ? Wv : Wo;
  u16* th = WTh + (size_t)z * 262144;
  u16* tl = WTl + (size_t)z * 262144;
  __shared__ float tile[64][65];
  const int r0 = blockIdx.y * 64, c0 = blockIdx.x * 64;
#pragma unroll
  for (int j = 0; j < 16; ++j) {
    int fid = threadIdx.x + 256 * j;
    int r = fid >> 6, c = fid & 63;
    tile[r][c] = W[(size_t)(r0 + r) * 512 + c0 + c];
  }
  __syncthreads();
#pragma unroll
  for (int j = 0; j < 16; ++j) {
    int fid = threadIdx.x + 256 * j;
    int n = fid >> 6, kk = fid & 63;
    float v = tile[kk][n];
    u16 h = bf16r(v);
    th[(size_t)(c0 + n) * 512 + r0 + kk] = h;
    tl[(size_t)(c0 + n) * 512 + r0 + kk] = bf16r(v - bf2f(h));
  }
}

// ---------------- QKV projection (MFMA, 64-row m-tiles). Q,K split ------------
__global__ __launch_bounds__(256) void k_qkv(const u16* __restrict__ xh, const u16* __restrict__ xl,
                                             const u16* __restrict__ WTh, const u16* __restrict__ WTl,
                                             const float* __restrict__ bq, const float* __restrict__ bk,
                                             const float* __restrict__ bv,
                                             float* __restrict__ qo, float* __restrict__ ko, float* __restrict__ vo) {
  const int z = blockIdx.z;
  const bool split = (z < 2);                     // Q,K feed the top-k scores: fp32-grade
  const u16* Bh_ = WTh + (size_t)z * 262144;
  const u16* Bl_ = WTl + (size_t)z * 262144;
  const float* bias = (z == 0) ? bq : (z == 1) ? bk : bv;
  float* out = (z == 0) ? qo : (z == 1) ? ko : vo;
  const int n0 = blockIdx.x * 64, m0 = blockIdx.y * 64;
  const int l = threadIdx.x & 63, w = threadIdx.x >> 6;
  const int lr = l & 15, lk = (l >> 4) * 8;
  const int arow = m0 + 16 * w + lr;
  f32x4 acc[4];
#pragma unroll
  for (int i = 0; i < 4; ++i) { float b = bias[n0 + 16 * i + lr]; acc[i] = (f32x4){b, b, b, b}; }
  for (int ks = 0; ks < 16; ++ks) {
    const int kb2 = ks * 32 + lk;
    bf16x8 A  = *(const bf16x8*)(xh + (size_t)arow * 512 + kb2);
    bf16x8 Al = {};
    if (split) Al = *(const bf16x8*)(xl + (size_t)arow * 512 + kb2);
#pragma unroll
    for (int i = 0; i < 4; ++i) {
      bf16x8 Bf = *(const bf16x8*)(Bh_ + (size_t)(n0 + 16 * i + lr) * 512 + kb2);
      acc[i] = __builtin_amdgcn_mfma_f32_16x16x32_bf16(A, Bf, acc[i], 0, 0, 0);
      if (split) {
        bf16x8 Bl2 = *(const bf16x8*)(Bl_ + (size_t)(n0 + 16 * i + lr) * 512 + kb2);
        acc[i] = __builtin_amdgcn_mfma_f32_16x16x32_bf16(A, Bl2, acc[i], 0, 0, 0);
        acc[i] = __builtin_amdgcn_mfma_f32_16x16x32_bf16(Al, Bf, acc[i], 0, 0, 0);
      }
    }
  }
#pragma unroll
  for (int i = 0; i < 4; ++i)
#pragma unroll
    for (int r = 0; r < 4; ++r) {
      int m = m0 + 16 * w + (l >> 4) * 4 + r;
      int n = n0 + 16 * i + lr;
      int b_ = m >> 9, t = m & 511, h_ = n >> 6, dh = n & 63;
      out[(((size_t)(b_ * 8 + h_)) * 512 + t) * 64 + dh] = acc[i][r];
    }
}

// ---------------- inverse L2 norms over time for Q and K ----------------------
__global__ __launch_bounds__(256) void k_ssq(const float* __restrict__ qf, const float* __restrict__ kf,
                                             float* __restrict__ sinv) {
  const int bh = blockIdx.x, which = blockIdx.y;
  const float* Xb = (which ? kf : qf) + (size_t)bh * T_ * 64;
  const int tid = threadIdx.x;
  __shared__ float red[256];
  float ss = 0.f;
  for (int i = 0; i < 128; ++i) { float v = Xb[tid + 256 * i]; ss += v * v; }
  red[tid] = ss;
  __syncthreads();
  if (tid < 64) {
    float s = red[tid] + red[tid + 64] + red[tid + 128] + red[tid + 192];
    sinv[which * 2048 + bh * 64 + tid] = 1.0f / sqrtf(fmaxf(s, 1e-8f));
  }
}

// ---------------- pack: Q^T hi/lo, K^T duplicated hi/lo, V duplicated ---------
__global__ __launch_bounds__(256) void k_pack(const float* __restrict__ qf, const float* __restrict__ kf,
                                              const float* __restrict__ vf, const float* __restrict__ sinv,
                                              u16* __restrict__ QTh, u16* __restrict__ QTl,
                                              u16* __restrict__ KTh, u16* __restrict__ KTl,
                                              u16* __restrict__ V2) {
  const int t0 = blockIdx.x * 64, bh = blockIdx.y;
  const int tid = threadIdx.x;
  __shared__ float tile[64][65];
  // ---- Q: normalize, transpose, hi/lo ----
#pragma unroll
  for (int j = 0; j < 16; ++j) {
    int fid = tid + 256 * j;
    int r = fid >> 6, c = fid & 63;
    tile[r][c] = qf[((size_t)bh * 512 + t0 + r) * 64 + c] * sinv[bh * 64 + c];
  }
  __syncthreads();
#pragma unroll
  for (int j = 0; j < 16; ++j) {
    int fid = tid + 256 * j;
    int c = fid >> 6, tl2 = fid & 63;
    float v = tile[tl2][c];
    u16 hh = bf16r(v);
    size_t dst = ((size_t)bh * 64 + c) * 512 + t0 + tl2;
    QTh[dst] = hh;
    QTl[dst] = bf16r(v - bf2f(hh));
  }
  __syncthreads();
  // ---- K: normalize, transpose, duplicate in t, hi/lo ----
#pragma unroll
  for (int j = 0; j < 16; ++j) {
    int fid = tid + 256 * j;
    int r = fid >> 6, c = fid & 63;
    tile[r][c] = kf[((size_t)bh * 512 + t0 + r) * 64 + c] * sinv[2048 + bh * 64 + c];
  }
  __syncthreads();
#pragma unroll
  for (int j = 0; j < 16; ++j) {
    int fid = tid + 256 * j;
    int c = fid >> 6, tl2 = fid & 63;
    float v = tile[tl2][c];
    u16 hh = bf16r(v);
    u16 ll = bf16r(v - bf2f(hh));
    size_t base = ((size_t)bh * 64 + c) * 1024 + t0 + tl2;
    KTh[base] = hh;       KTl[base] = ll;
    KTh[base + 512] = hh; KTl[base + 512] = ll;
  }
  // ---- V: duplicate rows, single bf16, natural layout ----
#pragma unroll
  for (int j = 0; j < 4; ++j) {
    int r = (tid >> 4) + 16 * j, c4 = (tid & 15) * 4;
    float4 v4 = *(const float4*)(vf + ((size_t)bh * 512 + t0 + r) * 64 + c4);
    ushort4 o = make_ushort4(bf16r(v4.x), bf16r(v4.y), bf16r(v4.z), bf16r(v4.w));
    size_t base = ((size_t)bh * 1024 + t0 + r) * 64 + c4;
    *(ushort4*)(V2 + base) = o;
    *(ushort4*)(V2 + base + 512 * 64) = o;
  }
}

// ---------------- cov (MFMA, 3-product hi/lo), 4-way k-split per block --------
// KT is [bh][64][1024] t-duplicated: lag shift = contiguous offset. Aligned
// dwordx4 loads always; odd shifts realigned in-register via v_alignbit.
// 4 waves each do K=128, then 2-phase LDS reduce (32KB).
__global__ __launch_bounds__(256, 4) void k_cov(const u16* __restrict__ KTh, const u16* __restrict__ KTl,
                                                const u16* __restrict__ QTh, const u16* __restrict__ QTl,
                                                float* __restrict__ cov, float* __restrict__ score,
                                                const float* __restrict__ p_lambda) {
  const int li = blockIdx.x;                      // 0 => lag0; 1..64 => candidates
  const int bh = blockIdx.y;
  const int lag = (li == 0) ? 0 : lag_of(li - 1);
  const int tid = threadIdx.x, l = tid & 63, w = tid >> 6;
  const int lr = l & 15, lk = (l >> 4) * 8;
  __shared__ f32x4 lred[2][1024];                 // 32 KB
  const int shift = 512 - lag;                    // 1..512
  const int sbase = shift & ~1;
  const int odd = shift & 1;
  const u16* qh = QTh + (size_t)bh * 32768 + (size_t)lr * 512 + w * 128 + lk;
  const u16* ql = QTl + (size_t)bh * 32768 + (size_t)lr * 512 + w * 128 + lk;
  const u16* kh = KTh + (size_t)bh * 65536 + (size_t)lr * 1024 + w * 128 + lk + sbase;
  const u16* kl = KTl + (size_t)bh * 65536 + (size_t)lr * 1024 + w * 128 + lk + sbase;
  f32x4 acc[4][4] = {};
#pragma unroll
  for (int kk = 0; kk < 4; ++kk) {
    const int o = kk * 32;
    bf16x8 Bh2[4], Bl2[4];
#pragma unroll
    for (int ni = 0; ni < 4; ++ni) {
      Bh2[ni] = *(const bf16x8*)(qh + ni * 8192 + o);
      Bl2[ni] = *(const bf16x8*)(ql + ni * 8192 + o);
    }
#pragma unroll
    for (int mi = 0; mi < 4; ++mi) {
      bf16x8 Ah = load_shift8(kh + mi * 16384 + o, odd);
      bf16x8 Al = load_shift8(kl + mi * 16384 + o, odd);
#pragma unroll
      for (int ni = 0; ni < 4; ++ni) {
        acc[mi][ni] = __builtin_amdgcn_mfma_f32_16x16x32_bf16(Ah, Bh2[ni], acc[mi][ni], 0, 0, 0);
        acc[mi][ni] = __builtin_amdgcn_mfma_f32_16x16x32_bf16(Ah, Bl2[ni], acc[mi][ni], 0, 0, 0);
        acc[mi][ni] = __builtin_amdgcn_mfma_f32_16x16x32_bf16(Al, Bh2[ni], acc[mi][ni], 0, 0, 0);
      }
    }
  }
  // 2-phase cross-wave reduction
  if (w >= 2) {
#pragma unroll
    for (int mi = 0; mi < 4; ++mi)
#pragma unroll
      for (int ni = 0; ni < 4; ++ni) lred[w - 2][(mi * 4 + ni) * 64 + l] = acc[mi][ni];
  }
  __syncthreads();
  if (w < 2) {
#pragma unroll
    for (int mi = 0; mi < 4; ++mi)
#pragma unroll
      for (int ni = 0; ni < 4; ++ni) acc[mi][ni] += lred[w][(mi * 4 + ni) * 64 + l];
  }
  __syncthreads();
  if (w == 1) {
#pragma unroll
    for (int mi = 0; mi < 4; ++mi)
#pragma unroll
      for (int ni = 0; ni < 4; ++ni) lred[0][(mi * 4 + ni) * 64 + l] = acc[mi][ni];
  }
  __syncthreads();
  if (w == 0) {
#pragma unroll
    for (int mi = 0; mi < 4; ++mi)
#pragma unroll
      for (int ni = 0; ni < 4; ++ni) acc[mi][ni] += lred[0][(mi * 4 + ni) * 64 + l];
    float* cb = cov + ((size_t)li * BH + bh) * 4096;
    float labs = 0.f, ldiag = 0.f;
#pragma unroll
    for (int mi = 0; mi < 4; ++mi)
#pragma unroll
      for (int ni = 0; ni < 4; ++ni)
#pragma unroll
        for (int r = 0; r < 4; ++r) {
          int d = 16 * mi + (l >> 4) * 4 + r;
          int c = 16 * ni + lr;
          float vv = acc[mi][ni][r];
          cb[(size_t)d * 64 + c] = vv;
          labs += fabsf(vv);
          if (d == c) ldiag += fabsf(vv);
        }
#pragma unroll
    for (int off = 32; off > 0; off >>= 1) {
      labs += __shfl_xor(labs, off);
      ldiag += __shfl_xor(ldiag, off);
    }
    if (l == 0 && li > 0) {
      float lam = fminf(fmaxf(p_lambda[0], 0.f), 1.f);
      score[(size_t)bh * NLAG + (li - 1)] = lam * ldiag + (1.f - lam) * (labs - ldiag);
    }
  }
}

// ---------------- top-18: one wave per bh, register-resident argmax -----------
__global__ void k_topk(const float* __restrict__ score, int* __restrict__ sel,
                       float* __restrict__ wgt, const float* __restrict__ p_log_tau_lag) {
  const int bh = blockIdx.x;
  const int lane = threadIdx.x;        // 64 lanes = 1 wave
  float sc = score[(size_t)bh * NLAG + lane];
  float ts[KTOP];
  int ti[KTOP];
#pragma unroll
  for (int k = 0; k < KTOP; ++k) {
    float v = sc;
    int idx = lane;
#pragma unroll
    for (int off = 32; off > 0; off >>= 1) {
      float ov = __shfl_xor(v, off);
      int oi = __shfl_xor(idx, off);
      if (ov > v || (ov == v && oi < idx)) { v = ov; idx = oi; }
    }
    ts[k] = v;
    ti[k] = idx;
    if (lane == idx) sc = -3e38f;      // remove winner (tie -> lowest index, like lax.top_k)
  }
  const float tau_lag = fmaxf(expf(p_log_tau_lag[0]), 1e-4f);
  const float mx = ts[0];
  float e[KTOP];
  float sum = 0.f;
#pragma unroll
  for (int k = 0; k < KTOP; ++k) { e[k] = expf((ts[k] - mx) / tau_lag); sum += e[k]; }
  const float rs = 1.0f / sum;
  if (lane < KTOP) {
    sel[bh * KTOP + lane] = ti[lane];
    wgt[bh * KTOP + lane] = e[lane] * rs;
  }
}

// ---------------- softmax + scale + transpose -> single bf16 ------------------
__global__ __launch_bounds__(256) void k_attsm(const float* __restrict__ cov, const int* __restrict__ sel,
                                               const float* __restrict__ wgt,
                                               u16* __restrict__ attT,
                                               const float* __restrict__ p_log_tau,
                                               const float* __restrict__ p_beta) {
  const int bh = blockIdx.x, m = blockIdx.y;
  const int slot = (m == 0) ? 0 : (1 + (sel[bh * KTOP + m - 1] & 63));
  const float beta = fminf(fmaxf(p_beta[0], 0.f), 1.f);
  const float smv = (m == 0) ? (1.f - beta) : (beta * wgt[bh * KTOP + m - 1]);
  const float itau = 1.f / fmaxf(expf(p_log_tau[0]), 1e-4f);
  const float* cb = cov + ((size_t)slot * BH + bh) * 4096;
  __shared__ float att_s[64][66];
  const int lane = threadIdx.x & 63, wv = threadIdx.x >> 6;
  for (int d = wv; d < 64; d += 4) {
    float v = cb[(size_t)d * 64 + lane] * itau;
    float mx = v;
#pragma unroll
    for (int off = 32; off > 0; off >>= 1) mx = fmaxf(mx, __shfl_xor(mx, off));
    float e = expf(v - mx);
    float sm2 = e;
#pragma unroll
    for (int off = 32; off > 0; off >>= 1) sm2 += __shfl_xor(sm2, off);
    att_s[d][lane] = (e / sm2) * smv;
  }
  __syncthreads();
  u16* th = attT + ((size_t)m * BH + bh) * 4096;
#pragma unroll
  for (int j = 0; j < 16; ++j) {
    int fid = threadIdx.x + 256 * j;
    int c = fid >> 6, dl2 = fid & 63;
    th[(size_t)c * 64 + dl2] = bf16r(att_s[dl2][c]);
  }
}

// ---------------- weighted contrib sum: m-split across waves + LDS reduce -----
__global__ __launch_bounds__(256) void k_contrib(const u16* __restrict__ V2,
                                                 const u16* __restrict__ attT,
                                                 const int* __restrict__ sel,
                                                 u16* __restrict__ oh) {
  const int tt = blockIdx.x;                 // 32-row t-tiles: 0..15
  const int bh = blockIdx.y;
  const int b_ = bh >> 3, h_ = bh & 7;
  const int t0 = tt * 32;
  const int tid = threadIdx.x, l = tid & 63, w = tid >> 6;
  const int lr = l & 15, lk = (l >> 4) * 8;
  __shared__ f32x4 lred[2][512];             // 16 KB
  f32x4 acc[2][4] = {};
  const u16* Vb = V2 + (size_t)bh * 65536;
  const int mstart[5] = {0, 5, 10, 15, 19};
  for (int m = mstart[w]; m < mstart[w + 1]; ++m) {
    const int lag = (m == 0) ? 0 : lag_of(sel[bh * KTOP + m - 1] & 63);
    const u16* ab = attT + ((size_t)m * BH + bh) * 4096;
#pragma unroll
    for (int ks = 0; ks < 2; ++ks) {
      const int kb2 = ks * 32 + lk;
      bf16x8 Bf[4];
#pragma unroll
      for (int ni = 0; ni < 4; ++ni) Bf[ni] = *(const bf16x8*)(ab + (size_t)(16 * ni + lr) * 64 + kb2);
#pragma unroll
      for (int mi = 0; mi < 2; ++mi) {
        const int ub = t0 + 16 * mi + 512 - lag + lr;
        bf16x8 A = *(const bf16x8*)(Vb + (size_t)ub * 64 + kb2);
#pragma unroll
        for (int ni = 0; ni < 4; ++ni)
          acc[mi][ni] = __builtin_amdgcn_mfma_f32_16x16x32_bf16(A, Bf[ni], acc[mi][ni], 0, 0, 0);
      }
    }
  }
  if (w >= 2) {
#pragma unroll
    for (int mi = 0; mi < 2; ++mi)
#pragma unroll
      for (int ni = 0; ni < 4; ++ni) lred[w - 2][(mi * 4 + ni) * 64 + l] = acc[mi][ni];
  }
  __syncthreads();
  if (w < 2) {
#pragma unroll
    for (int mi = 0; mi < 2; ++mi)
#pragma unroll
      for (int ni = 0; ni < 4; ++ni) acc[mi][ni] += lred[w][(mi * 4 + ni) * 64 + l];
  }
  __syncthreads();
  if (w == 1) {
#pragma unroll
    for (int mi = 0; mi < 2; ++mi)
#pragma unroll
      for (int ni = 0; ni < 4; ++ni) lred[0][(mi * 4 + ni) * 64 + l] = acc[mi][ni];
  }
  __syncthreads();
  if (w == 0) {
#pragma unroll
    for (int mi = 0; mi < 2; ++mi)
#pragma unroll
      for (int ni = 0; ni < 4; ++ni) {
        acc[mi][ni] += lred[0][(mi * 4 + ni) * 64 + l];
#pragma unroll
        for (int r = 0; r < 4; ++r) {
          int t = t0 + 16 * mi + (l >> 4) * 4 + r;
          int c = 16 * ni + lr;
          oh[((size_t)b_ * 512 + t) * 512 + h_ * 64 + c] = bf16r(acc[mi][ni][r]);
        }
      }
  }
}

// ---------------- final projection (MFMA, single bf16, 64-row m-tiles) --------
__global__ __launch_bounds__(256) void k_out(const u16* __restrict__ oh,
                                             const u16* __restrict__ WTh,
                                             const float* __restrict__ bo, float* __restrict__ out) {
  const u16* Bh_ = WTh + (size_t)3 * 262144;
  const int n0 = blockIdx.x * 64, m0 = blockIdx.y * 64;
  const int l = threadIdx.x & 63, w = threadIdx.x >> 6;
  const int lr = l & 15, lk = (l >> 4) * 8;
  const int arow = m0 + 16 * w + lr;
  f32x4 acc[4];
#pragma unroll
  for (int i = 0; i < 4; ++i) { float b = bo[n0 + 16 * i + lr]; acc[i] = (f32x4){b, b, b, b}; }
  for (int ks = 0; ks < 16; ++ks) {
    int kb2 = ks * 32 + lk;
    bf16x8 A = *(const bf16x8*)(oh + (size_t)arow * 512 + kb2);
#pragma unroll
    for (int i = 0; i < 4; ++i) {
      bf16x8 Bf = *(const bf16x8*)(Bh_ + (size_t)(n0 + 16 * i + lr) * 512 + kb2);
      acc[i] = __builtin_amdgcn_mfma_f32_16x16x32_bf16(A, Bf, acc[i], 0, 0, 0);
    }
  }
#pragma unroll
  for (int i = 0; i < 4; ++i)
#pragma unroll
    for (int r = 0; r < 4; ++r) {
      int m = m0 + 16 * w + (l >> 4) * 4 + r;
      int n = n0 + 16 * i + lr;
      out[(size_t)m * 512 + n] = acc[i][r];
    }
}

}  // namespace

extern "C" void kernel_launch(void* const* d_in, const int* in_sizes, int n_in,
                              void* d_out, int out_size, void* d_ws, size_t ws_size,
                              hipStream_t stream) {
  (void)in_sizes; (void)n_in; (void)out_size; (void)ws_size;
  const float* x  = (const float*)d_in[0];
  const float* Wq = (const float*)d_in[1];
  const float* bq = (const float*)d_in[2];
  const float* Wk = (const float*)d_in[3];
  const float* bk = (const float*)d_in[4];
  const float* Wv = (const float*)d_in[5];
  const float* bv = (const float*)d_in[6];
  const float* Wo = (const float*)d_in[7];
  const float* bo = (const float*)d_in[8];
  const float* p_log_tau     = (const float*)d_in[9];
  const float* p_lambda      = (const float*)d_in[10];
  const float* p_beta        = (const float*)d_in[11];
  const float* p_log_tau_lag = (const float*)d_in[12];

  char* ws = (char*)d_ws;
  const size_t MB = 1ull << 20;
  u16*   xh    = (u16*)(ws + 0 * MB);     // 2 MB
  u16*   xl    = (u16*)(ws + 2 * MB);     // 2 MB
  u16*   WTh   = (u16*)(ws + 4 * MB);     // 2 MB (q,k,v,o)
  u16*   WTl   = (u16*)(ws + 6 * MB);     // 2 MB
  u16*   QTh   = (u16*)(ws + 8 * MB);     // 2 MB  [bh][64][512]
  u16*   QTl   = (u16*)(ws + 10 * MB);    // 2 MB
  u16*   KTh   = (u16*)(ws + 12 * MB);    // 4 MB  [bh][64][1024] t-duplicated
  u16*   KTl   = (u16*)(ws + 16 * MB);    // 4 MB
  u16*   V2    = (u16*)(ws + 20 * MB);    // 4 MB  [bh][1024][64]
  float* qf    = (float*)(ws + 24 * MB);  // 4 MB (dead after k_pack)
  float* kf    = (float*)(ws + 28 * MB);  // 4 MB (dead after k_pack)
  float* vf    = (float*)(ws + 32 * MB);  // 4 MB (dead after k_pack)
  u16*   attT  = (u16*)(ws + 24 * MB);    // 4.75 MB overlay on qf/kf (after k_pack)
  u16*   oh    = (u16*)(ws + 32 * MB);    // 2 MB overlay on vf (after k_pack)
  float* cov   = (float*)(ws + 36 * MB);  // 34 MB
  float* score = (float*)(ws + 70 * MB);          // 8 KB
  float* wgt   = (float*)(ws + 70 * MB + 16384);  // 2.3 KB
  int*   sel   = (int*)(ws + 70 * MB + 32768);    // 2.3 KB
  float* sinv  = (float*)(ws + 70 * MB + 49152);  // 16 KB [2][32][64]

  const dim3 blk(256);

  k_prep_x<<<dim3(1024), blk, 0, stream>>>(x, xh, xl);
  k_prep_w<<<dim3(8, 8, 4), blk, 0, stream>>>(Wq, Wk, Wv, Wo, WTh, WTl);
  k_qkv<<<dim3(8, 32, 3), blk, 0, stream>>>(xh, xl, WTh, WTl, bq, bk, bv, qf, kf, vf);
  k_ssq<<<dim3(32, 2), blk, 0, stream>>>(qf, kf, sinv);
  k_pack<<<dim3(8, 32), blk, 0, stream>>>(qf, kf, vf, sinv, QTh, QTl, KTh, KTl, V2);
  k_cov<<<dim3(65, 32), blk, 0, stream>>>(KTh, KTl, QTh, QTl, cov, score, p_lambda);
  k_topk<<<dim3(32), dim3(64), 0, stream>>>(score, sel, wgt, p_log_tau_lag);
  k_attsm<<<dim3(32, 19), blk, 0, stream>>>(cov, sel, wgt, attT, p_log_tau, p_beta);
  k_contrib<<<dim3(16, 32), blk, 0, stream>>>(V2, attT, sel, oh);
  k_out<<<dim3(8, 32), blk, 0, stream>>>(oh, WTh, bo, (float*)d_out);
}